// Round 1
// baseline (913.721 us; speedup 1.0000x reference)
//
#include <hip/hip_runtime.h>
#include <stdint.h>

// positional_spiking_attention — MFMA rewrite.
// All GEMM A-operands are spikes in {0,1} (exact in bf16). Weights are split
// w = hi + lo (two bf16 planes, Dekker): |pre_err| <= 512*max|w|*2^-16 ~ 8e-4
// worst-case. Spikes only depend on thresholds, so columns whose membrane is
// within EPS_FLAG of 0.5 are flagged and recomputed with the bit-exact serial
// fp32 FMA chain (which absmax==0.0 proved matches the harness reference).
//
// Workspace (111.1 MB of the >=128 MB ws):
//   0        xs_b   bf16 spikes of first LIF      [16384][512]
//   16M      qs     bf16 q spikes
//   32M      ks     bf16 k spikes
//   48M      vs     bf16 v spikes
//   64M      P1     fp32 pre-activations (33.5MB) -- reused per GEMM; later sA
//   96M      wsp    4 mats x 2 planes x 512x512 bf16 (4 MB)
//   100M     flags  3 x 4096 x 512 bytes (6 MB)

#define T_ 4
#define B_ 4
#define L_ 1024
#define D_ 512
#define BI_ (B_*L_)                 // 4096 rows per time step
#define M_ROWS (T_*B_*L_)           // 16384
#define STRIDE4 (B_*L_*D_/4)        // 524288 float4/ushort4 per t-slice
#define INV_STD 0.9999950000374997f
#define EPS_FLAG 3e-3f

typedef unsigned int   u32;
typedef unsigned short u16;
typedef __bf16 bf16x8 __attribute__((ext_vector_type(8)));
typedef float  f32x4  __attribute__((ext_vector_type(4)));

static __device__ __forceinline__ float spike_of(float m) {
  return m > 0.5f ? 1.0f : 0.0f;
}
static __device__ __forceinline__ u16 sbits(float s) {
  return s != 0.0f ? (u16)0x3F80 : (u16)0;
}

__device__ __forceinline__ void gll16(const u16* g, void* l) {
  __builtin_amdgcn_global_load_lds(
      (const __attribute__((address_space(1))) u32*)(const void*)g,
      (__attribute__((address_space(3))) u32*)l, 16, 0, 0);
}

// ---------------- weight split: w -> bf16 hi + bf16 lo ----------------
__global__ __launch_bounds__(256) void k_wsplit(const float* __restrict__ qw,
    const float* __restrict__ kw, const float* __restrict__ vw,
    const float* __restrict__ lw, u16* __restrict__ wsp) {
  int idx = blockIdx.x * 256 + threadIdx.x;   // 262144 total (4 mats x 65536 float4)
  int mat = idx >> 16;
  int u = idx & 65535;
  const float* W = mat == 0 ? qw : mat == 1 ? kw : mat == 2 ? vw : lw;
  float4 w = ((const float4*)W)[u];
  float wv[4] = {w.x, w.y, w.z, w.w};
  u16 hb[4], lb[4];
#pragma unroll
  for (int c = 0; c < 4; ++c) {
    __bf16 h = (__bf16)wv[c];
    float r = wv[c] - (float)h;       // exact (Sterbenz)
    __bf16 lo = (__bf16)r;
    hb[c] = __builtin_bit_cast(u16, h);
    lb[c] = __builtin_bit_cast(u16, lo);
  }
  u16* base = wsp + (size_t)mat * 524288;          // [mat][plane][e][d]
  ((ushort4*)base)[u]            = make_ushort4(hb[0], hb[1], hb[2], hb[3]);
  ((ushort4*)(base + 262144))[u] = make_ushort4(lb[0], lb[1], lb[2], lb[3]);
}

// ---------------- first LIF: x -> bf16 spikes ----------------
__global__ __launch_bounds__(256) void k_lif_first(const float* __restrict__ x,
                                                   u16* __restrict__ xsb) {
  int idx = blockIdx.x * 256 + threadIdx.x;
  if (idx >= STRIDE4) return;
  const float4* x4 = (const float4*)x;
  ushort4* o4 = (ushort4*)xsb;
  float m[4], s[4];
  float4 v = x4[idx];
  m[0] = v.x; m[1] = v.y; m[2] = v.z; m[3] = v.w;
#pragma unroll
  for (int c = 0; c < 4; ++c) s[c] = spike_of(m[c]);
  o4[idx] = make_ushort4(sbits(s[0]), sbits(s[1]), sbits(s[2]), sbits(s[3]));
#pragma unroll
  for (int t = 1; t < T_; ++t) {
    v = x4[idx + t * STRIDE4];
    float xv[4] = {v.x, v.y, v.z, v.w};
#pragma unroll
    for (int c = 0; c < 4; ++c) {
      m[c] = m[c] * 0.25f * (1.0f - s[c]) + xv[c];
      s[c] = spike_of(m[c]);
    }
    o4[idx + t * STRIDE4] = make_ushort4(sbits(s[0]), sbits(s[1]), sbits(s[2]), sbits(s[3]));
  }
}

// ---------------- MFMA GEMM + BN epilogue ----------------
// Y[r,e] = (sum_d A[r,d]*(Whi[e,d]+Wlo[e,d]) + bias[e]) * (INV_STD*gamma[e]) + beta[e]
// A: [16384][512] bf16 spikes. Wp: 2 planes of [512][512] bf16 (B^T form).
// 128x128 tile, BK=64, 4 waves each 64x64 (4x4 frags of 16x16x32).
// LDS: A 16KB | B 2x16KB, single-buffered 2-barrier loop (m97 structure).
// XOR swizzle ((r&7)<<4) on 16B slots; staging pre-swizzles the GLOBAL source
// so global_load_lds dest stays linear (both-sides-or-neither rule).
__global__ __launch_bounds__(256) void k_gemm(const u16* __restrict__ Ab,
    const u16* __restrict__ Wp, const float* __restrict__ bias,
    const float* __restrict__ gamma, const float* __restrict__ beta,
    float* __restrict__ Y) {
  __shared__ __align__(16) unsigned char sm[49152];
  const int tid = threadIdx.x;
  // XCD-chunked tile swizzle: 512 tiles, 8 XCDs -> 64 contiguous tiles each,
  // so a 16-row-panel's 4 col-blocks stay in one XCD L2.
  int f = blockIdx.y * 4 + blockIdx.x;
  int tI = (f & 7) * 64 + (f >> 3);
  const int row0 = (tI >> 2) * 128;
  const int col0 = (tI & 3) * 128;

  const u16* gsrc[12];
  int loff[12];
#pragma unroll
  for (int u = 0; u < 12; ++u) {
    if (u < 4) {                       // A region: 16 KB, rows of 64 bf16 (128 B)
      int lin = u * 4096 + tid * 16;
      int r = lin >> 7, slot = (lin >> 4) & 7, gs = slot ^ (r & 7);
      gsrc[u] = Ab + (size_t)(row0 + r) * 512 + gs * 8;
      loff[u] = lin;
    } else {                           // B region: 2 planes x 16 KB
      int lin = (u - 4) * 4096 + tid * 16;     // 0..32767
      int plane = lin >> 14, l3 = lin & 16383;
      int r = l3 >> 7, slot = (l3 >> 4) & 7, gs = slot ^ (r & 7);
      gsrc[u] = Wp + (size_t)plane * 262144 + (size_t)(col0 + r) * 512 + gs * 8;
      loff[u] = 16384 + lin;
    }
  }

  const int lane = tid & 63;
  const int wid = tid >> 6;
  const int wr = wid >> 1, wc = wid & 1;
  const int la = lane & 15, lg = lane >> 4;

  int offA[4][2], offB[2][4][2];
#pragma unroll
  for (int mi = 0; mi < 4; ++mi) {
    int r = wr * 64 + mi * 16 + la;
#pragma unroll
    for (int s = 0; s < 2; ++s)
      offA[mi][s] = r * 128 + ((s * 64 + lg * 16) ^ ((r & 7) << 4));
  }
#pragma unroll
  for (int p = 0; p < 2; ++p)
#pragma unroll
    for (int ni = 0; ni < 4; ++ni) {
      int r = wc * 64 + ni * 16 + la;
#pragma unroll
      for (int s = 0; s < 2; ++s)
        offB[p][ni][s] = 16384 + p * 16384 + r * 128 + ((s * 64 + lg * 16) ^ ((r & 7) << 4));
    }

  f32x4 acc[4][4];
#pragma unroll
  for (int a = 0; a < 4; ++a)
#pragma unroll
    for (int b = 0; b < 4; ++b) acc[a][b] = (f32x4){0.f, 0.f, 0.f, 0.f};

  for (int k0 = 0; k0 < 8; ++k0) {
#pragma unroll
    for (int u = 0; u < 12; ++u) gll16(gsrc[u] + (k0 << 6), sm + loff[u]);
    __syncthreads();                    // drains vmcnt (global_load_lds) + barrier
    uint4 af[4][2];
#pragma unroll
    for (int mi = 0; mi < 4; ++mi)
#pragma unroll
      for (int s = 0; s < 2; ++s)
        af[mi][s] = *(const uint4*)(sm + offA[mi][s]);
#pragma unroll
    for (int p = 0; p < 2; ++p)
#pragma unroll
      for (int s = 0; s < 2; ++s)
#pragma unroll
        for (int ni = 0; ni < 4; ++ni) {
          uint4 bf = *(const uint4*)(sm + offB[p][ni][s]);
#pragma unroll
          for (int mi = 0; mi < 4; ++mi)
            acc[mi][ni] = __builtin_amdgcn_mfma_f32_16x16x32_bf16(
                __builtin_bit_cast(bf16x8, af[mi][s]),
                __builtin_bit_cast(bf16x8, bf), acc[mi][ni], 0, 0, 0);
        }
    __syncthreads();
  }

  // epilogue: C/D layout col=lane&15, row=(lane>>4)*4+reg
#pragma unroll
  for (int ni = 0; ni < 4; ++ni) {
    int e = col0 + wc * 64 + ni * 16 + la;
    float cs = INV_STD * gamma[e];
    float cb = bias[e], ct = beta[e];
#pragma unroll
    for (int mi = 0; mi < 4; ++mi) {
      int rb = row0 + wr * 64 + mi * 16 + lg * 4;
#pragma unroll
      for (int p = 0; p < 4; ++p)
        Y[(size_t)(rb + p) * 512 + e] = (acc[mi][ni][p] + cb) * cs + ct;
    }
  }
}

// ---------------- LIF over pre-activations -> bf16 spikes + near-threshold flags
__global__ __launch_bounds__(256) void k_lif_s(const float* __restrict__ pre,
                                               u16* __restrict__ sp,
                                               unsigned char* __restrict__ fl) {
  int idx = blockIdx.x * 256 + threadIdx.x;
  if (idx >= STRIDE4) return;
  const float4* p4 = (const float4*)pre;
  ushort4* s4 = (ushort4*)sp;
  float m[4], s[4];
  unsigned char fb[4] = {0, 0, 0, 0};
  float4 v = p4[idx];
  m[0] = v.x; m[1] = v.y; m[2] = v.z; m[3] = v.w;
#pragma unroll
  for (int c = 0; c < 4; ++c) {
    s[c] = spike_of(m[c]);
    if (fabsf(m[c] - 0.5f) < EPS_FLAG) fb[c] = 1;
  }
  s4[idx] = make_ushort4(sbits(s[0]), sbits(s[1]), sbits(s[2]), sbits(s[3]));
#pragma unroll
  for (int t = 1; t < T_; ++t) {
    v = p4[idx + t * STRIDE4];
    float xv[4] = {v.x, v.y, v.z, v.w};
#pragma unroll
    for (int c = 0; c < 4; ++c) {
      m[c] = m[c] * 0.25f * (1.0f - s[c]) + xv[c];
      s[c] = spike_of(m[c]);
      if (fabsf(m[c] - 0.5f) < EPS_FLAG) fb[c] = 1;
    }
    s4[idx + t * STRIDE4] = make_ushort4(sbits(s[0]), sbits(s[1]), sbits(s[2]), sbits(s[3]));
  }
  ((uchar4*)fl)[idx] = make_uchar4(fb[0], fb[1], fb[2], fb[3]);
}

// ---------------- exact serial recompute of flagged columns ----------------
__global__ __launch_bounds__(256) void k_fixup(const u16* __restrict__ xsb,
    u16* __restrict__ qs, u16* __restrict__ ks, u16* __restrict__ vs,
    const float* __restrict__ qw, const float* __restrict__ qb2,
    const float* __restrict__ qg, const float* __restrict__ qbe,
    const float* __restrict__ kw, const float* __restrict__ kb2,
    const float* __restrict__ kg, const float* __restrict__ kbe,
    const float* __restrict__ vw, const float* __restrict__ vb2,
    const float* __restrict__ vg, const float* __restrict__ vbe,
    const unsigned char* __restrict__ flags) {
  const int tz = blockIdx.y;
  const int idx = blockIdx.x * 256 + threadIdx.x;   // 0..2097151 = (bi, d)
  const unsigned char* fl = flags + (size_t)tz * 2097152;
  if (!fl[idx]) return;
  const int bi = idx >> 9, d = idx & 511;
  const float* W  = tz == 0 ? qw  : tz == 1 ? kw  : vw;
  const float* Bb = tz == 0 ? qb2 : tz == 1 ? kb2 : vb2;
  const float* Gg = tz == 0 ? qg  : tz == 1 ? kg  : vg;
  const float* Be = tz == 0 ? qbe : tz == 1 ? kbe : vbe;
  u16* S          = tz == 0 ? qs  : tz == 1 ? ks  : vs;
  const float* wrow = W + (size_t)d * 512;
  const u16* a0 = xsb + (size_t)(0 * BI_ + bi) * 512;
  const u16* a1 = xsb + (size_t)(1 * BI_ + bi) * 512;
  const u16* a2 = xsb + (size_t)(2 * BI_ + bi) * 512;
  const u16* a3 = xsb + (size_t)(3 * BI_ + bi) * 512;
  float c0 = 0.f, c1 = 0.f, c2 = 0.f, c3 = 0.f;
#pragma unroll 4
  for (int j = 0; j < 512; ++j) {       // ascending-d serial fp32: matches reference
    float w = wrow[j];
    c0 += a0[j] ? w : 0.0f;
    c1 += a1[j] ? w : 0.0f;
    c2 += a2[j] ? w : 0.0f;
    c3 += a3[j] ? w : 0.0f;
  }
  float cs = INV_STD * Gg[d];
  float cb = Bb[d], ct = Be[d];
  float accs[4] = {c0, c1, c2, c3};
  float m = 0.f, s = 0.f;
#pragma unroll
  for (int t = 0; t < 4; ++t) {
    float pre = (accs[t] + cb) * cs + ct;   // identical expression to GEMM epilogue
    if (t == 0) m = pre;
    else m = m * 0.25f * (1.0f - s) + pre;
    s = spike_of(m);
    S[(size_t)(t * BI_ + bi) * 512 + d] = sbits(s);
  }
}

// ---------------- banded positional mixing + attn_lif (bf16 spikes in/out) ----
__global__ __launch_bounds__(256) void k_attn(const u16* __restrict__ qs,
    const u16* __restrict__ ks, const u16* __restrict__ vs,
    const float* __restrict__ pos_bias, u16* __restrict__ sout) {
  int idx = blockIdx.x * 256 + threadIdx.x;
  if (idx >= STRIDE4) return;
  const int d4 = idx & 127;
  const int bi = idx >> 7;
  const int i = bi & (L_ - 1);
  const int wmax = i < 7 ? i : 7;

  float pbv[8];
  const float* pbrow = pos_bias + (size_t)i * L_ + i;
  for (int w = 0; w <= wmax; ++w) pbv[w] = pbrow[-w];

  const ushort4* k4 = (const ushort4*)ks;
  const ushort4* v4 = (const ushort4*)vs;
  const ushort4* q4 = (const ushort4*)qs;
  float pre[T_][4];

#pragma unroll
  for (int t = 0; t < T_; ++t) {
    float sum[4] = {0.f, 0.f, 0.f, 0.f};
    const int tb = t * STRIDE4;
    for (int w = wmax; w >= 0; --w) {   // ascending j = i-w, matches reference order
      ushort4 ku = k4[tb + (bi - w) * 128 + d4];
      ushort4 vu = v4[tb + (bi - w) * 128 + d4];
      sum[0] += (ku.x && vu.x) ? pbv[w] : 0.0f;
      sum[1] += (ku.y && vu.y) ? pbv[w] : 0.0f;
      sum[2] += (ku.z && vu.z) ? pbv[w] : 0.0f;
      sum[3] += (ku.w && vu.w) ? pbv[w] : 0.0f;
    }
    ushort4 qu = q4[tb + bi * 128 + d4];
    pre[t][0] = qu.x ? sum[0] : 0.0f;
    pre[t][1] = qu.y ? sum[1] : 0.0f;
    pre[t][2] = qu.z ? sum[2] : 0.0f;
    pre[t][3] = qu.w ? sum[3] : 0.0f;
  }

  ushort4* s4 = (ushort4*)sout;
  float m[4], s[4];
#pragma unroll
  for (int c = 0; c < 4; ++c) { m[c] = pre[0][c]; s[c] = spike_of(m[c]); }
  s4[idx] = make_ushort4(sbits(s[0]), sbits(s[1]), sbits(s[2]), sbits(s[3]));
#pragma unroll
  for (int t = 1; t < T_; ++t) {
#pragma unroll
    for (int c = 0; c < 4; ++c) {
      m[c] = m[c] * 0.25f * (1.0f - s[c]) + pre[t][c];
      s[c] = spike_of(m[c]);
    }
    s4[idx + t * STRIDE4] = make_ushort4(sbits(s[0]), sbits(s[1]), sbits(s[2]), sbits(s[3]));
  }
}

extern "C" void kernel_launch(void* const* d_in, const int* in_sizes, int n_in,
                              void* d_out, int out_size, void* d_ws, size_t ws_size,
                              hipStream_t stream) {
  (void)in_sizes; (void)n_in; (void)out_size; (void)ws_size;
  const float* x        = (const float*)d_in[0];
  const float* pos_bias = (const float*)d_in[1];
  const float* q_w    = (const float*)d_in[2];
  const float* q_b    = (const float*)d_in[3];
  const float* q_g    = (const float*)d_in[4];
  const float* q_beta = (const float*)d_in[5];
  const float* k_w    = (const float*)d_in[6];
  const float* k_b    = (const float*)d_in[7];
  const float* k_g    = (const float*)d_in[8];
  const float* k_beta = (const float*)d_in[9];
  const float* v_w    = (const float*)d_in[10];
  const float* v_b    = (const float*)d_in[11];
  const float* v_g    = (const float*)d_in[12];
  const float* v_beta = (const float*)d_in[13];
  const float* last_w    = (const float*)d_in[14];
  const float* last_b    = (const float*)d_in[15];
  const float* last_g    = (const float*)d_in[16];
  const float* last_beta = (const float*)d_in[17];
  float* out = (float*)d_out;

  char* ws = (char*)d_ws;
  u16*   xsb  = (u16*)(ws + 0);
  u16*   qs   = (u16*)(ws + 16777216);
  u16*   ks   = (u16*)(ws + 33554432);
  u16*   vs   = (u16*)(ws + 50331648);
  float* P1   = (float*)(ws + 67108864);
  u16*   sA   = (u16*)(ws + 67108864);     // reuses P1 (dead by then)
  u16*   wsp  = (u16*)(ws + 100663296);
  unsigned char* flags = (unsigned char*)(ws + 104857600);

  dim3 gg(4, 128);

  k_wsplit<<<1024, 256, 0, stream>>>(q_w, k_w, v_w, last_w, wsp);
  k_lif_first<<<2048, 256, 0, stream>>>(x, xsb);

  k_gemm<<<gg, 256, 0, stream>>>(xsb, wsp + 0 * 524288, q_b, q_g, q_beta, P1);
  k_lif_s<<<2048, 256, 0, stream>>>(P1, qs, flags + 0 * 2097152);
  k_gemm<<<gg, 256, 0, stream>>>(xsb, wsp + 1 * 524288, k_b, k_g, k_beta, P1);
  k_lif_s<<<2048, 256, 0, stream>>>(P1, ks, flags + 1 * 2097152);
  k_gemm<<<gg, 256, 0, stream>>>(xsb, wsp + 2 * 524288, v_b, v_g, v_beta, P1);
  k_lif_s<<<2048, 256, 0, stream>>>(P1, vs, flags + 2 * 2097152);

  k_fixup<<<dim3(8192, 3), 256, 0, stream>>>(xsb, qs, ks, vs,
      q_w, q_b, q_g, q_beta, k_w, k_b, k_g, k_beta, v_w, v_b, v_g, v_beta, flags);

  k_attn<<<2048, 256, 0, stream>>>(qs, ks, vs, pos_bias, sA);

  k_gemm<<<gg, 256, 0, stream>>>(sA, wsp + 3 * 524288, last_b, last_g, last_beta, out);
}

// Round 2
// 414.754 us; speedup vs baseline: 2.2030x; 2.2030x over previous
//
#include <hip/hip_runtime.h>
#include <stdint.h>

// positional_spiking_attention — MFMA + compacted near-threshold fixup.
// GEMM A-operands are spikes in {0,1} (exact in bf16). Weights split
// w = hi + lo (two bf16 planes). Pre-activation error observed <= ~2.4e-4;
// columns whose membrane comes within EPS_FLAG=1e-3 of threshold at any t are
// appended (atomic compaction) and recomputed with the bit-exact serial fp32
// chain. Fixup waves are dense (one flagged column per lane).
//
// Workspace:
//   0        xs_b   bf16 spikes of first LIF      [16384][512]  (16MB)
//   16M      qs     bf16 q spikes
//   32M      ks     bf16 k spikes
//   48M      vs     bf16 v spikes
//   64M      P1     fp32 pre-activations (33.5MB) -- reused per GEMM; later sA
//   96M      wsp    4 mats x 2 planes x 512x512 bf16 (4 MB)
//   100M     list   u32 flagged-column ids (cap 5M = 20MB)
//   ~119M    cnt    u32 counter

#define T_ 4
#define B_ 4
#define L_ 1024
#define D_ 512
#define BI_ (B_*L_)                 // 4096 rows per time step
#define M_ROWS (T_*B_*L_)           // 16384
#define STRIDE4 (B_*L_*D_/4)        // 524288 float4/ushort4 per t-slice
#define INV_STD 0.9999950000374997f
#define EPS_FLAG 1e-3f
#define LIST_CAP 5000000u

typedef unsigned int   u32;
typedef unsigned short u16;
typedef __bf16 bf16x8 __attribute__((ext_vector_type(8)));
typedef float  f32x4  __attribute__((ext_vector_type(4)));

static __device__ __forceinline__ float spike_of(float m) {
  return m > 0.5f ? 1.0f : 0.0f;
}
static __device__ __forceinline__ u16 sbits(float s) {
  return s != 0.0f ? (u16)0x3F80 : (u16)0;
}

__device__ __forceinline__ void gll16(const u16* g, void* l) {
  __builtin_amdgcn_global_load_lds(
      (const __attribute__((address_space(1))) u32*)(const void*)g,
      (__attribute__((address_space(3))) u32*)l, 16, 0, 0);
}

// ---------------- zero the compaction counter ----------------
__global__ void k_zero(u32* cnt) { if (threadIdx.x == 0) *cnt = 0; }

// ---------------- weight split: w -> bf16 hi + bf16 lo ----------------
__global__ __launch_bounds__(256) void k_wsplit(const float* __restrict__ qw,
    const float* __restrict__ kw, const float* __restrict__ vw,
    const float* __restrict__ lw, u16* __restrict__ wsp) {
  int idx = blockIdx.x * 256 + threadIdx.x;   // 262144 total (4 mats x 65536 float4)
  int mat = idx >> 16;
  int u = idx & 65535;
  const float* W = mat == 0 ? qw : mat == 1 ? kw : mat == 2 ? vw : lw;
  float4 w = ((const float4*)W)[u];
  float wv[4] = {w.x, w.y, w.z, w.w};
  u16 hb[4], lb[4];
#pragma unroll
  for (int c = 0; c < 4; ++c) {
    __bf16 h = (__bf16)wv[c];
    float r = wv[c] - (float)h;
    __bf16 lo = (__bf16)r;
    hb[c] = __builtin_bit_cast(u16, h);
    lb[c] = __builtin_bit_cast(u16, lo);
  }
  u16* base = wsp + (size_t)mat * 524288;          // [mat][plane][e][d]
  ((ushort4*)base)[u]            = make_ushort4(hb[0], hb[1], hb[2], hb[3]);
  ((ushort4*)(base + 262144))[u] = make_ushort4(lb[0], lb[1], lb[2], lb[3]);
}

// ---------------- first LIF: x -> bf16 spikes ----------------
__global__ __launch_bounds__(256) void k_lif_first(const float* __restrict__ x,
                                                   u16* __restrict__ xsb) {
  int idx = blockIdx.x * 256 + threadIdx.x;
  if (idx >= STRIDE4) return;
  const float4* x4 = (const float4*)x;
  ushort4* o4 = (ushort4*)xsb;
  float m[4], s[4];
  float4 v = x4[idx];
  m[0] = v.x; m[1] = v.y; m[2] = v.z; m[3] = v.w;
#pragma unroll
  for (int c = 0; c < 4; ++c) s[c] = spike_of(m[c]);
  o4[idx] = make_ushort4(sbits(s[0]), sbits(s[1]), sbits(s[2]), sbits(s[3]));
#pragma unroll
  for (int t = 1; t < T_; ++t) {
    v = x4[idx + t * STRIDE4];
    float xv[4] = {v.x, v.y, v.z, v.w};
#pragma unroll
    for (int c = 0; c < 4; ++c) {
      m[c] = m[c] * 0.25f * (1.0f - s[c]) + xv[c];
      s[c] = spike_of(m[c]);
    }
    o4[idx + t * STRIDE4] = make_ushort4(sbits(s[0]), sbits(s[1]), sbits(s[2]), sbits(s[3]));
  }
}

// ---------------- MFMA GEMM + BN epilogue (unchanged structure) ----------------
__global__ __launch_bounds__(256) void k_gemm(const u16* __restrict__ Ab,
    const u16* __restrict__ Wp, const float* __restrict__ bias,
    const float* __restrict__ gamma, const float* __restrict__ beta,
    float* __restrict__ Y) {
  __shared__ __align__(16) unsigned char sm[49152];
  const int tid = threadIdx.x;
  int f = blockIdx.y * 4 + blockIdx.x;
  int tI = (f & 7) * 64 + (f >> 3);
  const int row0 = (tI >> 2) * 128;
  const int col0 = (tI & 3) * 128;

  const u16* gsrc[12];
  int loff[12];
#pragma unroll
  for (int u = 0; u < 12; ++u) {
    if (u < 4) {
      int lin = u * 4096 + tid * 16;
      int r = lin >> 7, slot = (lin >> 4) & 7, gs = slot ^ (r & 7);
      gsrc[u] = Ab + (size_t)(row0 + r) * 512 + gs * 8;
      loff[u] = lin;
    } else {
      int lin = (u - 4) * 4096 + tid * 16;
      int plane = lin >> 14, l3 = lin & 16383;
      int r = l3 >> 7, slot = (l3 >> 4) & 7, gs = slot ^ (r & 7);
      gsrc[u] = Wp + (size_t)plane * 262144 + (size_t)(col0 + r) * 512 + gs * 8;
      loff[u] = 16384 + lin;
    }
  }

  const int lane = tid & 63;
  const int wid = tid >> 6;
  const int wr = wid >> 1, wc = wid & 1;
  const int la = lane & 15, lg = lane >> 4;

  int offA[4][2], offB[2][4][2];
#pragma unroll
  for (int mi = 0; mi < 4; ++mi) {
    int r = wr * 64 + mi * 16 + la;
#pragma unroll
    for (int s = 0; s < 2; ++s)
      offA[mi][s] = r * 128 + ((s * 64 + lg * 16) ^ ((r & 7) << 4));
  }
#pragma unroll
  for (int p = 0; p < 2; ++p)
#pragma unroll
    for (int ni = 0; ni < 4; ++ni) {
      int r = wc * 64 + ni * 16 + la;
#pragma unroll
      for (int s = 0; s < 2; ++s)
        offB[p][ni][s] = 16384 + p * 16384 + r * 128 + ((s * 64 + lg * 16) ^ ((r & 7) << 4));
    }

  f32x4 acc[4][4];
#pragma unroll
  for (int a = 0; a < 4; ++a)
#pragma unroll
    for (int b = 0; b < 4; ++b) acc[a][b] = (f32x4){0.f, 0.f, 0.f, 0.f};

  for (int k0 = 0; k0 < 8; ++k0) {
#pragma unroll
    for (int u = 0; u < 12; ++u) gll16(gsrc[u] + (k0 << 6), sm + loff[u]);
    __syncthreads();
    uint4 af[4][2];
#pragma unroll
    for (int mi = 0; mi < 4; ++mi)
#pragma unroll
      for (int s = 0; s < 2; ++s)
        af[mi][s] = *(const uint4*)(sm + offA[mi][s]);
#pragma unroll
    for (int p = 0; p < 2; ++p)
#pragma unroll
      for (int s = 0; s < 2; ++s)
#pragma unroll
        for (int ni = 0; ni < 4; ++ni) {
          uint4 bf = *(const uint4*)(sm + offB[p][ni][s]);
#pragma unroll
          for (int mi = 0; mi < 4; ++mi)
            acc[mi][ni] = __builtin_amdgcn_mfma_f32_16x16x32_bf16(
                __builtin_bit_cast(bf16x8, af[mi][s]),
                __builtin_bit_cast(bf16x8, bf), acc[mi][ni], 0, 0, 0);
        }
    __syncthreads();
  }

#pragma unroll
  for (int ni = 0; ni < 4; ++ni) {
    int e = col0 + wc * 64 + ni * 16 + la;
    float cs = INV_STD * gamma[e];
    float cb = bias[e], ct = beta[e];
#pragma unroll
    for (int mi = 0; mi < 4; ++mi) {
      int rb = row0 + wr * 64 + mi * 16 + lg * 4;
#pragma unroll
      for (int p = 0; p < 4; ++p)
        Y[(size_t)(rb + p) * 512 + e] = (acc[mi][ni][p] + cb) * cs + ct;
    }
  }
}

// ------- LIF over pre-activations -> bf16 spikes + compacted flag list -------
__global__ __launch_bounds__(256) void k_lif_s(const float* __restrict__ pre,
                                               u16* __restrict__ sp,
                                               u32* __restrict__ list,
                                               u32* __restrict__ cnt,
                                               int tz) {
  int idx = blockIdx.x * 256 + threadIdx.x;
  if (idx >= STRIDE4) return;
  const float4* p4 = (const float4*)pre;
  ushort4* s4 = (ushort4*)sp;
  float m[4], s[4];
  int fb[4] = {0, 0, 0, 0};
  float4 v = p4[idx];
  m[0] = v.x; m[1] = v.y; m[2] = v.z; m[3] = v.w;
#pragma unroll
  for (int c = 0; c < 4; ++c) {
    s[c] = spike_of(m[c]);
    if (fabsf(m[c] - 0.5f) < EPS_FLAG) fb[c] = 1;
  }
  s4[idx] = make_ushort4(sbits(s[0]), sbits(s[1]), sbits(s[2]), sbits(s[3]));
#pragma unroll
  for (int t = 1; t < T_; ++t) {
    v = p4[idx + t * STRIDE4];
    float xv[4] = {v.x, v.y, v.z, v.w};
#pragma unroll
    for (int c = 0; c < 4; ++c) {
      m[c] = m[c] * 0.25f * (1.0f - s[c]) + xv[c];
      s[c] = spike_of(m[c]);
      if (fabsf(m[c] - 0.5f) < EPS_FLAG) fb[c] = 1;
    }
    s4[idx + t * STRIDE4] = make_ushort4(sbits(s[0]), sbits(s[1]), sbits(s[2]), sbits(s[3]));
  }
  int nf = fb[0] + fb[1] + fb[2] + fb[3];
  if (nf) {
    u32 base = atomicAdd(cnt, (u32)nf);
    const int bi = idx >> 7, d0 = (idx & 127) * 4;
    u32 p = base;
#pragma unroll
    for (int c = 0; c < 4; ++c)
      if (fb[c]) {
        if (p < LIST_CAP)
          list[p] = ((u32)tz << 21) | (u32)(bi * 512 + d0 + c);
        ++p;
      }
  }
}

// ------- exact serial recompute of flagged columns (dense over compacted list)
__global__ __launch_bounds__(256) void k_fixup_c(const u16* __restrict__ xsb,
    u16* __restrict__ qs, u16* __restrict__ ks, u16* __restrict__ vs,
    const float* __restrict__ qw, const float* __restrict__ qb2,
    const float* __restrict__ qg, const float* __restrict__ qbe,
    const float* __restrict__ kw, const float* __restrict__ kb2,
    const float* __restrict__ kg, const float* __restrict__ kbe,
    const float* __restrict__ vw, const float* __restrict__ vb2,
    const float* __restrict__ vg, const float* __restrict__ vbe,
    const u32* __restrict__ list, const u32* __restrict__ cnt) {
  u32 n = *cnt;
  if (n > LIST_CAP) n = LIST_CAP;
  for (u32 i = blockIdx.x * 256 + threadIdx.x; i < n; i += gridDim.x * 256) {
    u32 e = list[i];
    int tz = (int)(e >> 21);
    int col = (int)(e & 0x1FFFFFu);
    int bi = col >> 9, d = col & 511;
    const float* W  = tz == 0 ? qw  : tz == 1 ? kw  : vw;
    const float* Bb = tz == 0 ? qb2 : tz == 1 ? kb2 : vb2;
    const float* Gg = tz == 0 ? qg  : tz == 1 ? kg  : vg;
    const float* Be = tz == 0 ? qbe : tz == 1 ? kbe : vbe;
    u16* S          = tz == 0 ? qs  : tz == 1 ? ks  : vs;
    const float4* w4 = (const float4*)(W + (size_t)d * 512);
    const ushort4* A0 = (const ushort4*)(xsb + (size_t)(0 * BI_ + bi) * 512);
    const ushort4* A1 = (const ushort4*)(xsb + (size_t)(1 * BI_ + bi) * 512);
    const ushort4* A2 = (const ushort4*)(xsb + (size_t)(2 * BI_ + bi) * 512);
    const ushort4* A3 = (const ushort4*)(xsb + (size_t)(3 * BI_ + bi) * 512);
    float c0 = 0.f, c1 = 0.f, c2 = 0.f, c3 = 0.f;
#pragma unroll 4
    for (int g = 0; g < 64; ++g) {        // 8 j per group, ascending order kept
      float4 wa = w4[g * 2], wb = w4[g * 2 + 1];
      ushort4 r0a = A0[g * 2], r0b = A0[g * 2 + 1];
      ushort4 r1a = A1[g * 2], r1b = A1[g * 2 + 1];
      ushort4 r2a = A2[g * 2], r2b = A2[g * 2 + 1];
      ushort4 r3a = A3[g * 2], r3b = A3[g * 2 + 1];
      float wv[8] = {wa.x, wa.y, wa.z, wa.w, wb.x, wb.y, wb.z, wb.w};
      u16 r0[8] = {r0a.x, r0a.y, r0a.z, r0a.w, r0b.x, r0b.y, r0b.z, r0b.w};
      u16 r1[8] = {r1a.x, r1a.y, r1a.z, r1a.w, r1b.x, r1b.y, r1b.z, r1b.w};
      u16 r2[8] = {r2a.x, r2a.y, r2a.z, r2a.w, r2b.x, r2b.y, r2b.z, r2b.w};
      u16 r3[8] = {r3a.x, r3a.y, r3a.z, r3a.w, r3b.x, r3b.y, r3b.z, r3b.w};
#pragma unroll
      for (int u = 0; u < 8; ++u) {
        float w = wv[u];
        c0 += r0[u] ? w : 0.0f;
        c1 += r1[u] ? w : 0.0f;
        c2 += r2[u] ? w : 0.0f;
        c3 += r3[u] ? w : 0.0f;
      }
    }
    float cs = INV_STD * Gg[d];
    float cb = Bb[d], ct = Be[d];
    float accs[4] = {c0, c1, c2, c3};
    float m = 0.f, s = 0.f;
#pragma unroll
    for (int t = 0; t < 4; ++t) {
      float pre = (accs[t] + cb) * cs + ct;   // identical expression to GEMM epilogue
      if (t == 0) m = pre;
      else m = m * 0.25f * (1.0f - s) + pre;
      s = spike_of(m);
      S[(size_t)(t * BI_ + bi) * 512 + d] = sbits(s);
    }
  }
}

// ---------------- banded positional mixing + attn_lif ----------------
__global__ __launch_bounds__(256) void k_attn(const u16* __restrict__ qs,
    const u16* __restrict__ ks, const u16* __restrict__ vs,
    const float* __restrict__ pos_bias, u16* __restrict__ sout) {
  int idx = blockIdx.x * 256 + threadIdx.x;
  if (idx >= STRIDE4) return;
  const int d4 = idx & 127;
  const int bi = idx >> 7;
  const int i = bi & (L_ - 1);
  const int wmax = i < 7 ? i : 7;

  float pbv[8];
  const float* pbrow = pos_bias + (size_t)i * L_ + i;
  for (int w = 0; w <= wmax; ++w) pbv[w] = pbrow[-w];

  const ushort4* k4 = (const ushort4*)ks;
  const ushort4* v4 = (const ushort4*)vs;
  const ushort4* q4 = (const ushort4*)qs;
  float pre[T_][4];

#pragma unroll
  for (int t = 0; t < T_; ++t) {
    float sum[4] = {0.f, 0.f, 0.f, 0.f};
    const int tb = t * STRIDE4;
    for (int w = wmax; w >= 0; --w) {   // ascending j = i-w
      ushort4 ku = k4[tb + (bi - w) * 128 + d4];
      ushort4 vu = v4[tb + (bi - w) * 128 + d4];
      sum[0] += (ku.x && vu.x) ? pbv[w] : 0.0f;
      sum[1] += (ku.y && vu.y) ? pbv[w] : 0.0f;
      sum[2] += (ku.z && vu.z) ? pbv[w] : 0.0f;
      sum[3] += (ku.w && vu.w) ? pbv[w] : 0.0f;
    }
    ushort4 qu = q4[tb + bi * 128 + d4];
    pre[t][0] = qu.x ? sum[0] : 0.0f;
    pre[t][1] = qu.y ? sum[1] : 0.0f;
    pre[t][2] = qu.z ? sum[2] : 0.0f;
    pre[t][3] = qu.w ? sum[3] : 0.0f;
  }

  ushort4* s4 = (ushort4*)sout;
  float m[4], s[4];
#pragma unroll
  for (int c = 0; c < 4; ++c) { m[c] = pre[0][c]; s[c] = spike_of(m[c]); }
  s4[idx] = make_ushort4(sbits(s[0]), sbits(s[1]), sbits(s[2]), sbits(s[3]));
#pragma unroll
  for (int t = 1; t < T_; ++t) {
#pragma unroll
    for (int c = 0; c < 4; ++c) {
      m[c] = m[c] * 0.25f * (1.0f - s[c]) + pre[t][c];
      s[c] = spike_of(m[c]);
    }
    s4[idx + t * STRIDE4] = make_ushort4(sbits(s[0]), sbits(s[1]), sbits(s[2]), sbits(s[3]));
  }
}

extern "C" void kernel_launch(void* const* d_in, const int* in_sizes, int n_in,
                              void* d_out, int out_size, void* d_ws, size_t ws_size,
                              hipStream_t stream) {
  (void)in_sizes; (void)n_in; (void)out_size; (void)ws_size;
  const float* x        = (const float*)d_in[0];
  const float* pos_bias = (const float*)d_in[1];
  const float* q_w    = (const float*)d_in[2];
  const float* q_b    = (const float*)d_in[3];
  const float* q_g    = (const float*)d_in[4];
  const float* q_beta = (const float*)d_in[5];
  const float* k_w    = (const float*)d_in[6];
  const float* k_b    = (const float*)d_in[7];
  const float* k_g    = (const float*)d_in[8];
  const float* k_beta = (const float*)d_in[9];
  const float* v_w    = (const float*)d_in[10];
  const float* v_b    = (const float*)d_in[11];
  const float* v_g    = (const float*)d_in[12];
  const float* v_beta = (const float*)d_in[13];
  const float* last_w    = (const float*)d_in[14];
  const float* last_b    = (const float*)d_in[15];
  const float* last_g    = (const float*)d_in[16];
  const float* last_beta = (const float*)d_in[17];
  float* out = (float*)d_out;

  char* ws = (char*)d_ws;
  u16*   xsb  = (u16*)(ws + 0);
  u16*   qs   = (u16*)(ws + 16777216);
  u16*   ks   = (u16*)(ws + 33554432);
  u16*   vs   = (u16*)(ws + 50331648);
  float* P1   = (float*)(ws + 67108864);
  u16*   sA   = (u16*)(ws + 67108864);     // reuses P1 (dead by then)
  u16*   wsp  = (u16*)(ws + 100663296);
  u32*   list = (u32*)(ws + 104857600);    // 20 MB cap
  u32*   cnt  = (u32*)(ws + 124857600);

  dim3 gg(4, 128);

  k_zero<<<1, 64, 0, stream>>>(cnt);
  k_wsplit<<<1024, 256, 0, stream>>>(q_w, k_w, v_w, last_w, wsp);
  k_lif_first<<<2048, 256, 0, stream>>>(x, xsb);

  k_gemm<<<gg, 256, 0, stream>>>(xsb, wsp + 0 * 524288, q_b, q_g, q_beta, P1);
  k_lif_s<<<2048, 256, 0, stream>>>(P1, qs, list, cnt, 0);
  k_gemm<<<gg, 256, 0, stream>>>(xsb, wsp + 1 * 524288, k_b, k_g, k_beta, P1);
  k_lif_s<<<2048, 256, 0, stream>>>(P1, ks, list, cnt, 1);
  k_gemm<<<gg, 256, 0, stream>>>(xsb, wsp + 2 * 524288, v_b, v_g, v_beta, P1);
  k_lif_s<<<2048, 256, 0, stream>>>(P1, vs, list, cnt, 2);

  k_fixup_c<<<512, 256, 0, stream>>>(xsb, qs, ks, vs,
      q_w, q_b, q_g, q_beta, k_w, k_b, k_g, k_beta, v_w, v_b, v_g, v_beta,
      list, cnt);

  k_attn<<<2048, 256, 0, stream>>>(qs, ks, vs, pos_bias, sA);

  k_gemm<<<gg, 256, 0, stream>>>(sA, wsp + 3 * 524288, last_b, last_g, last_beta, out);
}

// Round 3
// 390.509 us; speedup vs baseline: 2.3398x; 1.0621x over previous
//
#include <hip/hip_runtime.h>
#include <stdint.h>

// positional_spiking_attention — MFMA + compacted near-threshold fixup (v3).
// GEMM A-operands are spikes in {0,1} (exact in bf16). Weights split
// w = hi + lo (two bf16 planes). Columns whose membrane comes within
// EPS_FLAG=1e-3 of threshold at any t are appended (atomic compaction) and
// recomputed with the bit-exact serial fp32 chain. Fixup v3: 1-wave blocks +
// double-buffered prefetch (v2 was latency-serialized at VGPR=16).
//
// Workspace:
//   0        xs_b   bf16 spikes of first LIF      [16384][512]  (16MB)
//   16M      qs     bf16 q spikes
//   32M      ks     bf16 k spikes
//   48M      vs     bf16 v spikes
//   64M      P1     fp32 pre-activations (33.5MB) -- reused per GEMM; later sA
//   96M      wsp    4 mats x 2 planes x 512x512 bf16 (4 MB)
//   100M     list   u32 flagged-column ids (cap 5M = 20MB)
//   ~119M    cnt    u32 counter

#define T_ 4
#define B_ 4
#define L_ 1024
#define D_ 512
#define BI_ (B_*L_)                 // 4096 rows per time step
#define M_ROWS (T_*B_*L_)           // 16384
#define STRIDE4 (B_*L_*D_/4)        // 524288 float4/ushort4 per t-slice
#define INV_STD 0.9999950000374997f
#define EPS_FLAG 1e-3f
#define LIST_CAP 5000000u

typedef unsigned int   u32;
typedef unsigned short u16;
typedef __bf16 bf16x8 __attribute__((ext_vector_type(8)));
typedef float  f32x4  __attribute__((ext_vector_type(4)));

static __device__ __forceinline__ float spike_of(float m) {
  return m > 0.5f ? 1.0f : 0.0f;
}
static __device__ __forceinline__ u16 sbits(float s) {
  return s != 0.0f ? (u16)0x3F80 : (u16)0;
}

__device__ __forceinline__ void gll16(const u16* g, void* l) {
  __builtin_amdgcn_global_load_lds(
      (const __attribute__((address_space(1))) u32*)(const void*)g,
      (__attribute__((address_space(3))) u32*)l, 16, 0, 0);
}

// ---------------- weight split: w -> bf16 hi + bf16 lo (+ cnt zero) ----------
__global__ __launch_bounds__(256) void k_wsplit(const float* __restrict__ qw,
    const float* __restrict__ kw, const float* __restrict__ vw,
    const float* __restrict__ lw, u16* __restrict__ wsp, u32* __restrict__ cnt) {
  int idx = blockIdx.x * 256 + threadIdx.x;   // 262144 total (4 mats x 65536 float4)
  if (idx == 0) *cnt = 0;
  int mat = idx >> 16;
  int u = idx & 65535;
  const float* W = mat == 0 ? qw : mat == 1 ? kw : mat == 2 ? vw : lw;
  float4 w = ((const float4*)W)[u];
  float wv[4] = {w.x, w.y, w.z, w.w};
  u16 hb[4], lb[4];
#pragma unroll
  for (int c = 0; c < 4; ++c) {
    __bf16 h = (__bf16)wv[c];
    float r = wv[c] - (float)h;
    __bf16 lo = (__bf16)r;
    hb[c] = __builtin_bit_cast(u16, h);
    lb[c] = __builtin_bit_cast(u16, lo);
  }
  u16* base = wsp + (size_t)mat * 524288;          // [mat][plane][e][d]
  ((ushort4*)base)[u]            = make_ushort4(hb[0], hb[1], hb[2], hb[3]);
  ((ushort4*)(base + 262144))[u] = make_ushort4(lb[0], lb[1], lb[2], lb[3]);
}

// ---------------- first LIF: x -> bf16 spikes ----------------
__global__ __launch_bounds__(256) void k_lif_first(const float* __restrict__ x,
                                                   u16* __restrict__ xsb) {
  int idx = blockIdx.x * 256 + threadIdx.x;
  if (idx >= STRIDE4) return;
  const float4* x4 = (const float4*)x;
  ushort4* o4 = (ushort4*)xsb;
  float m[4], s[4];
  float4 v = x4[idx];
  m[0] = v.x; m[1] = v.y; m[2] = v.z; m[3] = v.w;
#pragma unroll
  for (int c = 0; c < 4; ++c) s[c] = spike_of(m[c]);
  o4[idx] = make_ushort4(sbits(s[0]), sbits(s[1]), sbits(s[2]), sbits(s[3]));
#pragma unroll
  for (int t = 1; t < T_; ++t) {
    v = x4[idx + t * STRIDE4];
    float xv[4] = {v.x, v.y, v.z, v.w};
#pragma unroll
    for (int c = 0; c < 4; ++c) {
      m[c] = m[c] * 0.25f * (1.0f - s[c]) + xv[c];
      s[c] = spike_of(m[c]);
    }
    o4[idx + t * STRIDE4] = make_ushort4(sbits(s[0]), sbits(s[1]), sbits(s[2]), sbits(s[3]));
  }
}

// ---------------- MFMA GEMM + BN epilogue (unchanged) ----------------
__global__ __launch_bounds__(256) void k_gemm(const u16* __restrict__ Ab,
    const u16* __restrict__ Wp, const float* __restrict__ bias,
    const float* __restrict__ gamma, const float* __restrict__ beta,
    float* __restrict__ Y) {
  __shared__ __align__(16) unsigned char sm[49152];
  const int tid = threadIdx.x;
  int f = blockIdx.y * 4 + blockIdx.x;
  int tI = (f & 7) * 64 + (f >> 3);
  const int row0 = (tI >> 2) * 128;
  const int col0 = (tI & 3) * 128;

  const u16* gsrc[12];
  int loff[12];
#pragma unroll
  for (int u = 0; u < 12; ++u) {
    if (u < 4) {
      int lin = u * 4096 + tid * 16;
      int r = lin >> 7, slot = (lin >> 4) & 7, gs = slot ^ (r & 7);
      gsrc[u] = Ab + (size_t)(row0 + r) * 512 + gs * 8;
      loff[u] = lin;
    } else {
      int lin = (u - 4) * 4096 + tid * 16;
      int plane = lin >> 14, l3 = lin & 16383;
      int r = l3 >> 7, slot = (l3 >> 4) & 7, gs = slot ^ (r & 7);
      gsrc[u] = Wp + (size_t)plane * 262144 + (size_t)(col0 + r) * 512 + gs * 8;
      loff[u] = 16384 + lin;
    }
  }

  const int lane = tid & 63;
  const int wid = tid >> 6;
  const int wr = wid >> 1, wc = wid & 1;
  const int la = lane & 15, lg = lane >> 4;

  int offA[4][2], offB[2][4][2];
#pragma unroll
  for (int mi = 0; mi < 4; ++mi) {
    int r = wr * 64 + mi * 16 + la;
#pragma unroll
    for (int s = 0; s < 2; ++s)
      offA[mi][s] = r * 128 + ((s * 64 + lg * 16) ^ ((r & 7) << 4));
  }
#pragma unroll
  for (int p = 0; p < 2; ++p)
#pragma unroll
    for (int ni = 0; ni < 4; ++ni) {
      int r = wc * 64 + ni * 16 + la;
#pragma unroll
      for (int s = 0; s < 2; ++s)
        offB[p][ni][s] = 16384 + p * 16384 + r * 128 + ((s * 64 + lg * 16) ^ ((r & 7) << 4));
    }

  f32x4 acc[4][4];
#pragma unroll
  for (int a = 0; a < 4; ++a)
#pragma unroll
    for (int b = 0; b < 4; ++b) acc[a][b] = (f32x4){0.f, 0.f, 0.f, 0.f};

  for (int k0 = 0; k0 < 8; ++k0) {
#pragma unroll
    for (int u = 0; u < 12; ++u) gll16(gsrc[u] + (k0 << 6), sm + loff[u]);
    __syncthreads();
    uint4 af[4][2];
#pragma unroll
    for (int mi = 0; mi < 4; ++mi)
#pragma unroll
      for (int s = 0; s < 2; ++s)
        af[mi][s] = *(const uint4*)(sm + offA[mi][s]);
#pragma unroll
    for (int p = 0; p < 2; ++p)
#pragma unroll
      for (int s = 0; s < 2; ++s)
#pragma unroll
        for (int ni = 0; ni < 4; ++ni) {
          uint4 bf = *(const uint4*)(sm + offB[p][ni][s]);
#pragma unroll
          for (int mi = 0; mi < 4; ++mi)
            acc[mi][ni] = __builtin_amdgcn_mfma_f32_16x16x32_bf16(
                __builtin_bit_cast(bf16x8, af[mi][s]),
                __builtin_bit_cast(bf16x8, bf), acc[mi][ni], 0, 0, 0);
        }
    __syncthreads();
  }

#pragma unroll
  for (int ni = 0; ni < 4; ++ni) {
    int e = col0 + wc * 64 + ni * 16 + la;
    float cs = INV_STD * gamma[e];
    float cb = bias[e], ct = beta[e];
#pragma unroll
    for (int mi = 0; mi < 4; ++mi) {
      int rb = row0 + wr * 64 + mi * 16 + lg * 4;
#pragma unroll
      for (int p = 0; p < 4; ++p)
        Y[(size_t)(rb + p) * 512 + e] = (acc[mi][ni][p] + cb) * cs + ct;
    }
  }
}

// ------- LIF over pre-activations -> bf16 spikes + compacted flag list -------
__global__ __launch_bounds__(256) void k_lif_s(const float* __restrict__ pre,
                                               u16* __restrict__ sp,
                                               u32* __restrict__ list,
                                               u32* __restrict__ cnt,
                                               int tz) {
  int idx = blockIdx.x * 256 + threadIdx.x;
  if (idx >= STRIDE4) return;
  const float4* p4 = (const float4*)pre;
  ushort4* s4 = (ushort4*)sp;
  float m[4], s[4];
  int fb[4] = {0, 0, 0, 0};
  float4 v = p4[idx];
  m[0] = v.x; m[1] = v.y; m[2] = v.z; m[3] = v.w;
#pragma unroll
  for (int c = 0; c < 4; ++c) {
    s[c] = spike_of(m[c]);
    if (fabsf(m[c] - 0.5f) < EPS_FLAG) fb[c] = 1;
  }
  s4[idx] = make_ushort4(sbits(s[0]), sbits(s[1]), sbits(s[2]), sbits(s[3]));
#pragma unroll
  for (int t = 1; t < T_; ++t) {
    v = p4[idx + t * STRIDE4];
    float xv[4] = {v.x, v.y, v.z, v.w};
#pragma unroll
    for (int c = 0; c < 4; ++c) {
      m[c] = m[c] * 0.25f * (1.0f - s[c]) + xv[c];
      s[c] = spike_of(m[c]);
      if (fabsf(m[c] - 0.5f) < EPS_FLAG) fb[c] = 1;
    }
    s4[idx + t * STRIDE4] = make_ushort4(sbits(s[0]), sbits(s[1]), sbits(s[2]), sbits(s[3]));
  }
  int nf = fb[0] + fb[1] + fb[2] + fb[3];
  if (nf) {
    u32 base = atomicAdd(cnt, (u32)nf);
    const int bi = idx >> 7, d0 = (idx & 127) * 4;
    u32 p = base;
#pragma unroll
    for (int c = 0; c < 4; ++c)
      if (fb[c]) {
        if (p < LIST_CAP)
          list[p] = ((u32)tz << 21) | (u32)(bi * 512 + d0 + c);
        ++p;
      }
  }
}

// ------- fixup v3: 1-wave blocks, double-buffered prefetch, exact serial chain
__device__ __forceinline__ void consume32(const float4 (&wb)[8],
                                          const uint4 (&ab)[4][4],
                                          float& c0, float& c1,
                                          float& c2, float& c3) {
#pragma unroll
  for (int u = 0; u < 8; ++u) {           // u = group of 4 consecutive j
    float4 w = wb[u];
    uint4 t0 = ab[0][u >> 1], t1 = ab[1][u >> 1];
    uint4 t2 = ab[2][u >> 1], t3 = ab[3][u >> 1];
    u32 a0 = (u & 1) ? t0.z : t0.x, b0 = (u & 1) ? t0.w : t0.y;
    u32 a1 = (u & 1) ? t1.z : t1.x, b1 = (u & 1) ? t1.w : t1.y;
    u32 a2 = (u & 1) ? t2.z : t2.x, b2 = (u & 1) ? t2.w : t2.y;
    u32 a3 = (u & 1) ? t3.z : t3.x, b3 = (u & 1) ? t3.w : t3.y;
    // strict ascending-j order per chain (bit-exact vs reference)
    c0 += (a0 & 0xFFFFu) ? w.x : 0.0f;
    c0 += (a0 >> 16)     ? w.y : 0.0f;
    c0 += (b0 & 0xFFFFu) ? w.z : 0.0f;
    c0 += (b0 >> 16)     ? w.w : 0.0f;
    c1 += (a1 & 0xFFFFu) ? w.x : 0.0f;
    c1 += (a1 >> 16)     ? w.y : 0.0f;
    c1 += (b1 & 0xFFFFu) ? w.z : 0.0f;
    c1 += (b1 >> 16)     ? w.w : 0.0f;
    c2 += (a2 & 0xFFFFu) ? w.x : 0.0f;
    c2 += (a2 >> 16)     ? w.y : 0.0f;
    c2 += (b2 & 0xFFFFu) ? w.z : 0.0f;
    c2 += (b2 >> 16)     ? w.w : 0.0f;
    c3 += (a3 & 0xFFFFu) ? w.x : 0.0f;
    c3 += (a3 >> 16)     ? w.y : 0.0f;
    c3 += (b3 & 0xFFFFu) ? w.z : 0.0f;
    c3 += (b3 >> 16)     ? w.w : 0.0f;
  }
}

__global__ __launch_bounds__(64) void k_fixup_c(const u16* __restrict__ xsb,
    u16* __restrict__ qs, u16* __restrict__ ks, u16* __restrict__ vs,
    const float* __restrict__ qw, const float* __restrict__ qb2,
    const float* __restrict__ qg, const float* __restrict__ qbe,
    const float* __restrict__ kw, const float* __restrict__ kb2,
    const float* __restrict__ kg, const float* __restrict__ kbe,
    const float* __restrict__ vw, const float* __restrict__ vb2,
    const float* __restrict__ vg, const float* __restrict__ vbe,
    const u32* __restrict__ list, const u32* __restrict__ cnt) {
  u32 n = *cnt;
  if (n > LIST_CAP) n = LIST_CAP;
  for (u32 i = blockIdx.x * 64 + threadIdx.x; i < n; i += gridDim.x * 64) {
    u32 e = list[i];
    int tz = (int)(e >> 21);
    int col = (int)(e & 0x1FFFFFu);
    int bi = col >> 9, d = col & 511;
    const float* W  = tz == 0 ? qw  : tz == 1 ? kw  : vw;
    const float* Bb = tz == 0 ? qb2 : tz == 1 ? kb2 : vb2;
    const float* Gg = tz == 0 ? qg  : tz == 1 ? kg  : vg;
    const float* Be = tz == 0 ? qbe : tz == 1 ? kbe : vbe;
    u16* S          = tz == 0 ? qs  : tz == 1 ? ks  : vs;
    const float4* w4 = (const float4*)(W + (size_t)d * 512);  // 128 float4
    const uint4* R0 = (const uint4*)(xsb + (size_t)(0 * BI_ + bi) * 512);
    const uint4* R1 = (const uint4*)(xsb + (size_t)(1 * BI_ + bi) * 512);
    const uint4* R2 = (const uint4*)(xsb + (size_t)(2 * BI_ + bi) * 512);
    const uint4* R3 = (const uint4*)(xsb + (size_t)(3 * BI_ + bi) * 512);

    float4 wA[8], wB[8];
    uint4 aA[4][4], aB[4][4];
    // prologue: chunk 0 -> A
#pragma unroll
    for (int u = 0; u < 8; ++u) wA[u] = w4[u];
#pragma unroll
    for (int u = 0; u < 4; ++u) {
      aA[0][u] = R0[u]; aA[1][u] = R1[u]; aA[2][u] = R2[u]; aA[3][u] = R3[u];
    }
    float c0 = 0.f, c1 = 0.f, c2 = 0.f, c3 = 0.f;
#pragma unroll
    for (int ch = 0; ch < 16; ++ch) {     // 16 chunks x 32 j
      if ((ch & 1) == 0) {
        if (ch + 1 < 16) {                // prefetch ch+1 -> B
          int wb0 = (ch + 1) * 8, ab0 = (ch + 1) * 4;
#pragma unroll
          for (int u = 0; u < 8; ++u) wB[u] = w4[wb0 + u];
#pragma unroll
          for (int u = 0; u < 4; ++u) {
            aB[0][u] = R0[ab0 + u]; aB[1][u] = R1[ab0 + u];
            aB[2][u] = R2[ab0 + u]; aB[3][u] = R3[ab0 + u];
          }
        }
        consume32(wA, aA, c0, c1, c2, c3);
      } else {
        if (ch + 1 < 16) {                // prefetch ch+1 -> A
          int wb0 = (ch + 1) * 8, ab0 = (ch + 1) * 4;
#pragma unroll
          for (int u = 0; u < 8; ++u) wA[u] = w4[wb0 + u];
#pragma unroll
          for (int u = 0; u < 4; ++u) {
            aA[0][u] = R0[ab0 + u]; aA[1][u] = R1[ab0 + u];
            aA[2][u] = R2[ab0 + u]; aA[3][u] = R3[ab0 + u];
          }
        }
        consume32(wB, aB, c0, c1, c2, c3);
      }
    }
    float cs = INV_STD * Gg[d];
    float cb = Bb[d], ct = Be[d];
    float accs[4] = {c0, c1, c2, c3};
    float m = 0.f, s = 0.f;
#pragma unroll
    for (int t = 0; t < 4; ++t) {
      float pre = (accs[t] + cb) * cs + ct;   // identical expression to GEMM epilogue
      if (t == 0) m = pre;
      else m = m * 0.25f * (1.0f - s) + pre;
      s = spike_of(m);
      S[(size_t)(t * BI_ + bi) * 512 + d] = sbits(s);
    }
  }
}

// ---------------- banded positional mixing + attn_lif ----------------
__global__ __launch_bounds__(256) void k_attn(const u16* __restrict__ qs,
    const u16* __restrict__ ks, const u16* __restrict__ vs,
    const float* __restrict__ pos_bias, u16* __restrict__ sout) {
  int idx = blockIdx.x * 256 + threadIdx.x;
  if (idx >= STRIDE4) return;
  const int d4 = idx & 127;
  const int bi = idx >> 7;
  const int i = bi & (L_ - 1);
  const int wmax = i < 7 ? i : 7;

  float pbv[8];
  const float* pbrow = pos_bias + (size_t)i * L_ + i;
  for (int w = 0; w <= wmax; ++w) pbv[w] = pbrow[-w];

  const ushort4* k4 = (const ushort4*)ks;
  const ushort4* v4 = (const ushort4*)vs;
  const ushort4* q4 = (const ushort4*)qs;
  float pre[T_][4];

#pragma unroll
  for (int t = 0; t < T_; ++t) {
    float sum[4] = {0.f, 0.f, 0.f, 0.f};
    const int tb = t * STRIDE4;
    for (int w = wmax; w >= 0; --w) {   // ascending j = i-w
      ushort4 ku = k4[tb + (bi - w) * 128 + d4];
      ushort4 vu = v4[tb + (bi - w) * 128 + d4];
      sum[0] += (ku.x && vu.x) ? pbv[w] : 0.0f;
      sum[1] += (ku.y && vu.y) ? pbv[w] : 0.0f;
      sum[2] += (ku.z && vu.z) ? pbv[w] : 0.0f;
      sum[3] += (ku.w && vu.w) ? pbv[w] : 0.0f;
    }
    ushort4 qu = q4[tb + bi * 128 + d4];
    pre[t][0] = qu.x ? sum[0] : 0.0f;
    pre[t][1] = qu.y ? sum[1] : 0.0f;
    pre[t][2] = qu.z ? sum[2] : 0.0f;
    pre[t][3] = qu.w ? sum[3] : 0.0f;
  }

  ushort4* s4 = (ushort4*)sout;
  float m[4], s[4];
#pragma unroll
  for (int c = 0; c < 4; ++c) { m[c] = pre[0][c]; s[c] = spike_of(m[c]); }
  s4[idx] = make_ushort4(sbits(s[0]), sbits(s[1]), sbits(s[2]), sbits(s[3]));
#pragma unroll
  for (int t = 1; t < T_; ++t) {
#pragma unroll
    for (int c = 0; c < 4; ++c) {
      m[c] = m[c] * 0.25f * (1.0f - s[c]) + pre[t][c];
      s[c] = spike_of(m[c]);
    }
    s4[idx + t * STRIDE4] = make_ushort4(sbits(s[0]), sbits(s[1]), sbits(s[2]), sbits(s[3]));
  }
}

extern "C" void kernel_launch(void* const* d_in, const int* in_sizes, int n_in,
                              void* d_out, int out_size, void* d_ws, size_t ws_size,
                              hipStream_t stream) {
  (void)in_sizes; (void)n_in; (void)out_size; (void)ws_size;
  const float* x        = (const float*)d_in[0];
  const float* pos_bias = (const float*)d_in[1];
  const float* q_w    = (const float*)d_in[2];
  const float* q_b    = (const float*)d_in[3];
  const float* q_g    = (const float*)d_in[4];
  const float* q_beta = (const float*)d_in[5];
  const float* k_w    = (const float*)d_in[6];
  const float* k_b    = (const float*)d_in[7];
  const float* k_g    = (const float*)d_in[8];
  const float* k_beta = (const float*)d_in[9];
  const float* v_w    = (const float*)d_in[10];
  const float* v_b    = (const float*)d_in[11];
  const float* v_g    = (const float*)d_in[12];
  const float* v_beta = (const float*)d_in[13];
  const float* last_w    = (const float*)d_in[14];
  const float* last_b    = (const float*)d_in[15];
  const float* last_g    = (const float*)d_in[16];
  const float* last_beta = (const float*)d_in[17];
  float* out = (float*)d_out;

  char* ws = (char*)d_ws;
  u16*   xsb  = (u16*)(ws + 0);
  u16*   qs   = (u16*)(ws + 16777216);
  u16*   ks   = (u16*)(ws + 33554432);
  u16*   vs   = (u16*)(ws + 50331648);
  float* P1   = (float*)(ws + 67108864);
  u16*   sA   = (u16*)(ws + 67108864);     // reuses P1 (dead by then)
  u16*   wsp  = (u16*)(ws + 100663296);
  u32*   list = (u32*)(ws + 104857600);    // 20 MB cap
  u32*   cnt  = (u32*)(ws + 124857600);

  dim3 gg(4, 128);

  k_wsplit<<<1024, 256, 0, stream>>>(q_w, k_w, v_w, last_w, wsp, cnt);
  k_lif_first<<<2048, 256, 0, stream>>>(x, xsb);

  k_gemm<<<gg, 256, 0, stream>>>(xsb, wsp + 0 * 524288, q_b, q_g, q_beta, P1);
  k_lif_s<<<2048, 256, 0, stream>>>(P1, qs, list, cnt, 0);
  k_gemm<<<gg, 256, 0, stream>>>(xsb, wsp + 1 * 524288, k_b, k_g, k_beta, P1);
  k_lif_s<<<2048, 256, 0, stream>>>(P1, ks, list, cnt, 1);
  k_gemm<<<gg, 256, 0, stream>>>(xsb, wsp + 2 * 524288, v_b, v_g, v_beta, P1);
  k_lif_s<<<2048, 256, 0, stream>>>(P1, vs, list, cnt, 2);

  k_fixup_c<<<2048, 64, 0, stream>>>(xsb, qs, ks, vs,
      q_w, q_b, q_g, q_beta, k_w, k_b, k_g, k_beta, v_w, v_b, v_g, v_beta,
      list, cnt);

  k_attn<<<2048, 256, 0, stream>>>(qs, ks, vs, pos_bias, sA);

  k_gemm<<<gg, 256, 0, stream>>>(sA, wsp + 3 * 524288, last_b, last_g, last_beta, out);
}

// Round 4
// 366.542 us; speedup vs baseline: 2.4928x; 1.0654x over previous
//
#include <hip/hip_runtime.h>
#include <stdint.h>

// positional_spiking_attention — MFMA with fused LIF epilogue (v4).
// Row layout for all spike matrices: r = bi*4 + t  (bi = b*L + l, t = time).
// With MFMA C/D layout row=(lane>>4)*4+reg, each lane's f32x4 accumulator
// holds all T=4 time steps of one (bi, e) column -> LIF recurrence is
// lane-local in the GEMM epilogue (no P1 buffer, no separate LIF pass).
// Weights split w = hi + lo (two bf16 planes); near-threshold columns
// (|m-0.5| < 1e-3 > 3.3e-4 worst-case bf16-split error) are compacted and
// recomputed with the bit-exact serial ascending fp32 chain (quad-per-item).
//
// Workspace:
//   0    xsb  bf16 first-LIF spikes [bi*4+t][512] (16MB)
//   16M  qs   bf16 q spikes (same layout)
//   32M  ks
//   48M  vs
//   64M  sA   bf16 attn spikes (same layout)
//   96M  wsp  4 mats x 2 planes x 512x512 bf16 (4MB)
//   100M list u32 flagged-column ids (cap 5M)
//   ~119M cnt u32 counter

#define T_ 4
#define B_ 4
#define L_ 1024
#define D_ 512
#define BI_ (B_*L_)                 // 4096 (b,l) columns
#define M_ROWS (T_*B_*L_)           // 16384
#define STRIDE4 (B_*L_*D_/4)        // 524288 float4/ushort4 per t-slice
#define INV_STD 0.9999950000374997f
#define EPS_FLAG 1e-3f
#define LIST_CAP 5000000u

typedef unsigned int   u32;
typedef unsigned short u16;
typedef __bf16 bf16x8 __attribute__((ext_vector_type(8)));
typedef float  f32x4  __attribute__((ext_vector_type(4)));

static __device__ __forceinline__ float spike_of(float m) {
  return m > 0.5f ? 1.0f : 0.0f;
}
static __device__ __forceinline__ u16 sbits(float s) {
  return s != 0.0f ? (u16)0x3F80 : (u16)0;
}

__device__ __forceinline__ void gll16(const u16* g, void* l) {
  __builtin_amdgcn_global_load_lds(
      (const __attribute__((address_space(1))) u32*)(const void*)g,
      (__attribute__((address_space(3))) u32*)l, 16, 0, 0);
}

// ---------------- weight split: w -> bf16 hi + bf16 lo (+ cnt zero) ----------
__global__ __launch_bounds__(256) void k_wsplit(const float* __restrict__ qw,
    const float* __restrict__ kw, const float* __restrict__ vw,
    const float* __restrict__ lw, u16* __restrict__ wsp, u32* __restrict__ cnt) {
  int idx = blockIdx.x * 256 + threadIdx.x;   // 262144 (4 mats x 65536 float4)
  if (idx == 0) *cnt = 0;
  int mat = idx >> 16;
  int u = idx & 65535;
  const float* W = mat == 0 ? qw : mat == 1 ? kw : mat == 2 ? vw : lw;
  float4 w = ((const float4*)W)[u];
  float wv[4] = {w.x, w.y, w.z, w.w};
  u16 hb[4], lb[4];
#pragma unroll
  for (int c = 0; c < 4; ++c) {
    __bf16 h = (__bf16)wv[c];
    float r = wv[c] - (float)h;
    __bf16 lo = (__bf16)r;
    hb[c] = __builtin_bit_cast(u16, h);
    lb[c] = __builtin_bit_cast(u16, lo);
  }
  u16* base = wsp + (size_t)mat * 524288;          // [mat][plane][e][d]
  ((ushort4*)base)[u]            = make_ushort4(hb[0], hb[1], hb[2], hb[3]);
  ((ushort4*)(base + 262144))[u] = make_ushort4(lb[0], lb[1], lb[2], lb[3]);
}

// ---------------- first LIF: x[t][bi][d] -> xsb[bi*4+t][d] ----------------
__global__ __launch_bounds__(256) void k_lif_first(const float* __restrict__ x,
                                                   u16* __restrict__ xsb) {
  int idx = blockIdx.x * 256 + threadIdx.x;       // bi*128 + d4
  if (idx >= STRIDE4) return;
  const int bi = idx >> 7, d4 = idx & 127;
  const float4* x4 = (const float4*)x;
  ushort4* o4 = (ushort4*)xsb;
  float m[4], s[4];
  float4 v = x4[idx];
  m[0] = v.x; m[1] = v.y; m[2] = v.z; m[3] = v.w;
#pragma unroll
  for (int c = 0; c < 4; ++c) s[c] = spike_of(m[c]);
  o4[(bi * 4 + 0) * 128 + d4] =
      make_ushort4(sbits(s[0]), sbits(s[1]), sbits(s[2]), sbits(s[3]));
#pragma unroll
  for (int t = 1; t < T_; ++t) {
    v = x4[idx + t * STRIDE4];
    float xv[4] = {v.x, v.y, v.z, v.w};
#pragma unroll
    for (int c = 0; c < 4; ++c) {
      m[c] = m[c] * 0.25f * (1.0f - s[c]) + xv[c];
      s[c] = spike_of(m[c]);
    }
    o4[(bi * 4 + t) * 128 + d4] =
        make_ushort4(sbits(s[0]), sbits(s[1]), sbits(s[2]), sbits(s[3]));
  }
}

// ======= shared GEMM core (macro-free via inline): 128x128 tile, BK=64 =======
// Computes acc[4][4] (f32x4) for this thread; A,Wp as in v3.
__device__ __forceinline__ void gemm_core(const u16* __restrict__ Ab,
    const u16* __restrict__ Wp, int row0, int col0, int tid,
    unsigned char* sm, f32x4 (&acc)[4][4]) {
  const u16* gsrc[12];
  int loff[12];
#pragma unroll
  for (int u = 0; u < 12; ++u) {
    if (u < 4) {
      int lin = u * 4096 + tid * 16;
      int r = lin >> 7, slot = (lin >> 4) & 7, gs = slot ^ (r & 7);
      gsrc[u] = Ab + (size_t)(row0 + r) * 512 + gs * 8;
      loff[u] = lin;
    } else {
      int lin = (u - 4) * 4096 + tid * 16;
      int plane = lin >> 14, l3 = lin & 16383;
      int r = l3 >> 7, slot = (l3 >> 4) & 7, gs = slot ^ (r & 7);
      gsrc[u] = Wp + (size_t)plane * 262144 + (size_t)(col0 + r) * 512 + gs * 8;
      loff[u] = 16384 + lin;
    }
  }
  const int lane = tid & 63;
  const int wid = tid >> 6;
  const int wr = wid >> 1, wc = wid & 1;
  const int la = lane & 15, lg = lane >> 4;

  int offA[4][2], offB[2][4][2];
#pragma unroll
  for (int mi = 0; mi < 4; ++mi) {
    int r = wr * 64 + mi * 16 + la;
#pragma unroll
    for (int s = 0; s < 2; ++s)
      offA[mi][s] = r * 128 + ((s * 64 + lg * 16) ^ ((r & 7) << 4));
  }
#pragma unroll
  for (int p = 0; p < 2; ++p)
#pragma unroll
    for (int ni = 0; ni < 4; ++ni) {
      int r = wc * 64 + ni * 16 + la;
#pragma unroll
      for (int s = 0; s < 2; ++s)
        offB[p][ni][s] = 16384 + p * 16384 + r * 128 +
                         ((s * 64 + lg * 16) ^ ((r & 7) << 4));
    }

#pragma unroll
  for (int a = 0; a < 4; ++a)
#pragma unroll
    for (int b = 0; b < 4; ++b) acc[a][b] = (f32x4){0.f, 0.f, 0.f, 0.f};

  for (int k0 = 0; k0 < 8; ++k0) {
#pragma unroll
    for (int u = 0; u < 12; ++u) gll16(gsrc[u] + (k0 << 6), sm + loff[u]);
    __syncthreads();
    uint4 af[4][2];
#pragma unroll
    for (int mi = 0; mi < 4; ++mi)
#pragma unroll
      for (int s = 0; s < 2; ++s)
        af[mi][s] = *(const uint4*)(sm + offA[mi][s]);
#pragma unroll
    for (int p = 0; p < 2; ++p)
#pragma unroll
      for (int s = 0; s < 2; ++s)
#pragma unroll
        for (int ni = 0; ni < 4; ++ni) {
          uint4 bf = *(const uint4*)(sm + offB[p][ni][s]);
#pragma unroll
          for (int mi = 0; mi < 4; ++mi)
            acc[mi][ni] = __builtin_amdgcn_mfma_f32_16x16x32_bf16(
                __builtin_bit_cast(bf16x8, af[mi][s]),
                __builtin_bit_cast(bf16x8, bf), acc[mi][ni], 0, 0, 0);
        }
    __syncthreads();
  }
}

// -------- GEMM + BN + LIF epilogue -> bf16 spikes + compacted flags ---------
__global__ __launch_bounds__(256) void k_gemm_lif(const u16* __restrict__ Ab,
    const u16* __restrict__ Wp, const float* __restrict__ bias,
    const float* __restrict__ gamma, const float* __restrict__ beta,
    u16* __restrict__ S, u32* __restrict__ list, u32* __restrict__ cnt,
    int tz) {
  __shared__ __align__(16) unsigned char sm[49152];
  const int tid = threadIdx.x;
  int f = blockIdx.y * 4 + blockIdx.x;
  int tI = (f & 7) * 64 + (f >> 3);
  const int row0 = (tI >> 2) * 128;
  const int col0 = (tI & 3) * 128;

  f32x4 acc[4][4];
  gemm_core(Ab, Wp, row0, col0, tid, sm, acc);

  const int lane = tid & 63;
  const int wid = tid >> 6;
  const int wr = wid >> 1, wc = wid & 1;
  const int la = lane & 15, lg = lane >> 4;

#pragma unroll
  for (int ni = 0; ni < 4; ++ni) {
    int e = col0 + wc * 64 + ni * 16 + la;
    float cs = INV_STD * gamma[e];
    float cb = bias[e], ct = beta[e];
#pragma unroll
    for (int mi = 0; mi < 4; ++mi) {
      int r = row0 + wr * 64 + mi * 16 + lg * 4;   // aligned: r = bi*4
      int bi = r >> 2;
      float m = 0.f, s = 0.f;
      int fl = 0;
      u16 sb[4];
#pragma unroll
      for (int p = 0; p < 4; ++p) {                // p == t
        float pre = (acc[mi][ni][p] + cb) * cs + ct;
        if (p == 0) m = pre;
        else m = m * 0.25f * (1.0f - s) + pre;
        s = spike_of(m);
        if (fabsf(m - 0.5f) < EPS_FLAG) fl = 1;
        sb[p] = sbits(s);
      }
#pragma unroll
      for (int p = 0; p < 4; ++p)
        S[(size_t)(r + p) * 512 + e] = sb[p];
      if (fl) {
        u32 pos = atomicAdd(cnt, 1u);
        if (pos < LIST_CAP)
          list[pos] = ((u32)tz << 21) | (u32)(bi * 512 + e);
      }
    }
  }
}

// -------- GEMM + BN epilogue -> fp32 out in [t][bi][d] layout ---------------
__global__ __launch_bounds__(256) void k_gemm_out(const u16* __restrict__ Ab,
    const u16* __restrict__ Wp, const float* __restrict__ bias,
    const float* __restrict__ gamma, const float* __restrict__ beta,
    float* __restrict__ Y) {
  __shared__ __align__(16) unsigned char sm[49152];
  const int tid = threadIdx.x;
  int f = blockIdx.y * 4 + blockIdx.x;
  int tI = (f & 7) * 64 + (f >> 3);
  const int row0 = (tI >> 2) * 128;
  const int col0 = (tI & 3) * 128;

  f32x4 acc[4][4];
  gemm_core(Ab, Wp, row0, col0, tid, sm, acc);

  const int lane = tid & 63;
  const int wid = tid >> 6;
  const int wr = wid >> 1, wc = wid & 1;
  const int la = lane & 15, lg = lane >> 4;

#pragma unroll
  for (int ni = 0; ni < 4; ++ni) {
    int e = col0 + wc * 64 + ni * 16 + la;
    float cs = INV_STD * gamma[e];
    float cb = bias[e], ct = beta[e];
#pragma unroll
    for (int mi = 0; mi < 4; ++mi) {
      int r = row0 + wr * 64 + mi * 16 + lg * 4;   // r = bi*4, p == t
      int bi = r >> 2;
#pragma unroll
      for (int p = 0; p < 4; ++p)
        Y[(size_t)(p * BI_ + bi) * 512 + e] = (acc[mi][ni][p] + cb) * cs + ct;
    }
  }
}

// ------- fixup v4: quad-per-item, exact serial chain per t, shfl-combine ----
__device__ __forceinline__ void consume32_1(const float4 (&wb)[8],
                                            const uint4 (&ab)[4], float& c) {
#pragma unroll
  for (int u = 0; u < 8; ++u) {           // u = group of 4 consecutive j
    float4 w = wb[u];
    uint4 tt = ab[u >> 1];
    u32 a = (u & 1) ? tt.z : tt.x, b = (u & 1) ? tt.w : tt.y;
    c += (a & 0xFFFFu) ? w.x : 0.0f;      // strict ascending-j order
    c += (a >> 16)     ? w.y : 0.0f;
    c += (b & 0xFFFFu) ? w.z : 0.0f;
    c += (b >> 16)     ? w.w : 0.0f;
  }
}

__global__ __launch_bounds__(128) void k_fixup_c(const u16* __restrict__ xsb,
    u16* __restrict__ qs, u16* __restrict__ ks, u16* __restrict__ vs,
    const float* __restrict__ qw, const float* __restrict__ qb2,
    const float* __restrict__ qg, const float* __restrict__ qbe,
    const float* __restrict__ kw, const float* __restrict__ kb2,
    const float* __restrict__ kg, const float* __restrict__ kbe,
    const float* __restrict__ vw, const float* __restrict__ vb2,
    const float* __restrict__ vg, const float* __restrict__ vbe,
    const u32* __restrict__ list, const u32* __restrict__ cnt) {
  u32 n = *cnt;
  if (n > LIST_CAP) n = LIST_CAP;
  u32 tot = n * 4;
  for (u32 ii = blockIdx.x * 128 + threadIdx.x; ii < tot;
       ii += gridDim.x * 128) {
    u32 i = ii >> 2;
    int t = (int)(ii & 3);
    u32 e = list[i];
    int tz = (int)(e >> 21);
    int col = (int)(e & 0x1FFFFFu);
    int bi = col >> 9, d = col & 511;
    const float* W  = tz == 0 ? qw  : tz == 1 ? kw  : vw;
    const float* Bb = tz == 0 ? qb2 : tz == 1 ? kb2 : vb2;
    const float* Gg = tz == 0 ? qg  : tz == 1 ? kg  : vg;
    const float* Be = tz == 0 ? qbe : tz == 1 ? kbe : vbe;
    u16* S          = tz == 0 ? qs  : tz == 1 ? ks  : vs;
    const float4* w4 = (const float4*)(W + (size_t)d * 512);          // 128
    const uint4*  R  = (const uint4*)(xsb + ((size_t)bi * 4 + t) * 512); // 32

    float4 wA[8], wB[8];
    uint4 aA[4], aB[4];
#pragma unroll
    for (int u = 0; u < 8; ++u) wA[u] = w4[u];
#pragma unroll
    for (int u = 0; u < 4; ++u) aA[u] = R[u];
    float c = 0.f;
#pragma unroll
    for (int ch = 0; ch < 16; ++ch) {     // 16 chunks x 32 j
      if ((ch & 1) == 0) {
        if (ch + 1 < 16) {
          int wb0 = (ch + 1) * 8, ab0 = (ch + 1) * 4;
#pragma unroll
          for (int u = 0; u < 8; ++u) wB[u] = w4[wb0 + u];
#pragma unroll
          for (int u = 0; u < 4; ++u) aB[u] = R[ab0 + u];
        }
        consume32_1(wA, aA, c);
      } else {
        if (ch + 1 < 16) {
          int wb0 = (ch + 1) * 8, ab0 = (ch + 1) * 4;
#pragma unroll
          for (int u = 0; u < 8; ++u) wA[u] = w4[wb0 + u];
#pragma unroll
          for (int u = 0; u < 4; ++u) aA[u] = R[ab0 + u];
        }
        consume32_1(wB, aB, c);
      }
    }
    // gather the quad's 4 chains (lanes quad-aligned; tot % 4 == 0)
    int lane = threadIdx.x & 63;
    int qb = lane & ~3;
    float cq[4];
    cq[0] = __shfl(c, qb + 0, 64);
    cq[1] = __shfl(c, qb + 1, 64);
    cq[2] = __shfl(c, qb + 2, 64);
    cq[3] = __shfl(c, qb + 3, 64);
    float cs = INV_STD * Gg[d];
    float cb = Bb[d], ct = Be[d];
    float m = 0.f, s = 0.f;
    u16 myb = 0;
#pragma unroll
    for (int t2 = 0; t2 < 4; ++t2) {
      float pre = (cq[t2] + cb) * cs + ct;   // identical to GEMM epilogue
      if (t2 == 0) m = pre;
      else m = m * 0.25f * (1.0f - s) + pre;
      s = spike_of(m);
      if (t2 == t) myb = sbits(s);
    }
    S[((size_t)bi * 4 + t) * 512 + d] = myb;
  }
}

// ---------------- banded positional mixing + attn_lif (new layout) ----------
__global__ __launch_bounds__(256) void k_attn(const u16* __restrict__ qs,
    const u16* __restrict__ ks, const u16* __restrict__ vs,
    const float* __restrict__ pos_bias, u16* __restrict__ sout) {
  int idx = blockIdx.x * 256 + threadIdx.x;     // bi*128 + d4
  if (idx >= STRIDE4) return;
  const int d4 = idx & 127;
  const int bi = idx >> 7;
  const int i = bi & (L_ - 1);
  const int wmax = i < 7 ? i : 7;

  float pbv[8];
  const float* pbrow = pos_bias + (size_t)i * L_ + i;
  for (int w = 0; w <= wmax; ++w) pbv[w] = pbrow[-w];

  const ushort4* k4 = (const ushort4*)ks;
  const ushort4* v4 = (const ushort4*)vs;
  const ushort4* q4 = (const ushort4*)qs;
  float pre[T_][4];

#pragma unroll
  for (int t = 0; t < T_; ++t) {
    float sum[4] = {0.f, 0.f, 0.f, 0.f};
    for (int w = wmax; w >= 0; --w) {   // ascending j = i-w
      int rj = ((bi - w) * 4 + t) * 128 + d4;
      ushort4 ku = k4[rj];
      ushort4 vu = v4[rj];
      sum[0] += (ku.x && vu.x) ? pbv[w] : 0.0f;
      sum[1] += (ku.y && vu.y) ? pbv[w] : 0.0f;
      sum[2] += (ku.z && vu.z) ? pbv[w] : 0.0f;
      sum[3] += (ku.w && vu.w) ? pbv[w] : 0.0f;
    }
    ushort4 qu = q4[(bi * 4 + t) * 128 + d4];
    pre[t][0] = qu.x ? sum[0] : 0.0f;
    pre[t][1] = qu.y ? sum[1] : 0.0f;
    pre[t][2] = qu.z ? sum[2] : 0.0f;
    pre[t][3] = qu.w ? sum[3] : 0.0f;
  }

  ushort4* s4 = (ushort4*)sout;
  float m[4], s[4];
#pragma unroll
  for (int c = 0; c < 4; ++c) { m[c] = pre[0][c]; s[c] = spike_of(m[c]); }
  s4[(bi * 4 + 0) * 128 + d4] =
      make_ushort4(sbits(s[0]), sbits(s[1]), sbits(s[2]), sbits(s[3]));
#pragma unroll
  for (int t = 1; t < T_; ++t) {
#pragma unroll
    for (int c = 0; c < 4; ++c) {
      m[c] = m[c] * 0.25f * (1.0f - s[c]) + pre[t][c];
      s[c] = spike_of(m[c]);
    }
    s4[(bi * 4 + t) * 128 + d4] =
        make_ushort4(sbits(s[0]), sbits(s[1]), sbits(s[2]), sbits(s[3]));
  }
}

extern "C" void kernel_launch(void* const* d_in, const int* in_sizes, int n_in,
                              void* d_out, int out_size, void* d_ws, size_t ws_size,
                              hipStream_t stream) {
  (void)in_sizes; (void)n_in; (void)out_size; (void)ws_size;
  const float* x        = (const float*)d_in[0];
  const float* pos_bias = (const float*)d_in[1];
  const float* q_w    = (const float*)d_in[2];
  const float* q_b    = (const float*)d_in[3];
  const float* q_g    = (const float*)d_in[4];
  const float* q_beta = (const float*)d_in[5];
  const float* k_w    = (const float*)d_in[6];
  const float* k_b    = (const float*)d_in[7];
  const float* k_g    = (const float*)d_in[8];
  const float* k_beta = (const float*)d_in[9];
  const float* v_w    = (const float*)d_in[10];
  const float* v_b    = (const float*)d_in[11];
  const float* v_g    = (const float*)d_in[12];
  const float* v_beta = (const float*)d_in[13];
  const float* last_w    = (const float*)d_in[14];
  const float* last_b    = (const float*)d_in[15];
  const float* last_g    = (const float*)d_in[16];
  const float* last_beta = (const float*)d_in[17];
  float* out = (float*)d_out;

  char* ws = (char*)d_ws;
  u16*   xsb  = (u16*)(ws + 0);
  u16*   qs   = (u16*)(ws + 16777216);
  u16*   ks   = (u16*)(ws + 33554432);
  u16*   vs   = (u16*)(ws + 50331648);
  u16*   sA   = (u16*)(ws + 67108864);
  u16*   wsp  = (u16*)(ws + 100663296);
  u32*   list = (u32*)(ws + 104857600);    // 20 MB cap
  u32*   cnt  = (u32*)(ws + 124857600);

  dim3 gg(4, 128);

  k_wsplit<<<1024, 256, 0, stream>>>(q_w, k_w, v_w, last_w, wsp, cnt);
  k_lif_first<<<2048, 256, 0, stream>>>(x, xsb);

  k_gemm_lif<<<gg, 256, 0, stream>>>(xsb, wsp + 0 * 524288, q_b, q_g, q_beta,
                                     qs, list, cnt, 0);
  k_gemm_lif<<<gg, 256, 0, stream>>>(xsb, wsp + 1 * 524288, k_b, k_g, k_beta,
                                     ks, list, cnt, 1);
  k_gemm_lif<<<gg, 256, 0, stream>>>(xsb, wsp + 2 * 524288, v_b, v_g, v_beta,
                                     vs, list, cnt, 2);

  k_fixup_c<<<2048, 128, 0, stream>>>(xsb, qs, ks, vs,
      q_w, q_b, q_g, q_beta, k_w, k_b, k_g, k_beta, v_w, v_b, v_g, v_beta,
      list, cnt);

  k_attn<<<2048, 256, 0, stream>>>(qs, ks, vs, pos_bias, sA);

  k_gemm_out<<<gg, 256, 0, stream>>>(sA, wsp + 3 * 524288,
                                     last_b, last_g, last_beta, out);
}

// Round 5
// 348.566 us; speedup vs baseline: 2.6214x; 1.0516x over previous
//
#include <hip/hip_runtime.h>
#include <stdint.h>

// positional_spiking_attention — MFMA, fused QKV dispatch + coalesced epilogues (v5).
// Row layout for all spike matrices: r = bi*4 + t  (bi = b*L + l, t = time).
// MFMA C/D layout row=(lane>>4)*4+reg -> each lane's f32x4 holds all T=4 time
// steps of one (bi,e) column -> LIF recurrence is lane-local in the epilogue.
// Weights split w = hi + lo (two bf16 planes); near-threshold columns
// (|m-0.5| < 1e-3) are compacted and recomputed with the bit-exact serial
// ascending fp32 chain (quad-per-item).
//
// Workspace:
//   0    xsb  bf16 first-LIF spikes [bi*4+t][512] (16MB)
//   16M  qs   bf16 q spikes (same layout)
//   32M  ks
//   48M  vs
//   64M  sA   bf16 attn spikes (same layout)
//   96M  wsp  4 mats x 2 planes x 512x512 bf16 (4MB)
//   100M list u32 flagged-column ids (cap 5M)
//   ~119M cnt u32 counter

#define T_ 4
#define B_ 4
#define L_ 1024
#define D_ 512
#define BI_ (B_*L_)                 // 4096 (b,l) columns
#define M_ROWS (T_*B_*L_)           // 16384
#define STRIDE4 (B_*L_*D_/4)        // 524288 float4/ushort4 per t-slice
#define INV_STD 0.9999950000374997f
#define EPS_FLAG 1e-3f
#define LIST_CAP 5000000u

typedef unsigned int   u32;
typedef unsigned short u16;
typedef __bf16 bf16x8 __attribute__((ext_vector_type(8)));
typedef float  f32x4  __attribute__((ext_vector_type(4)));

static __device__ __forceinline__ float spike_of(float m) {
  return m > 0.5f ? 1.0f : 0.0f;
}
static __device__ __forceinline__ u16 sbits(float s) {
  return s != 0.0f ? (u16)0x3F80 : (u16)0;
}

__device__ __forceinline__ void gll16(const u16* g, void* l) {
  __builtin_amdgcn_global_load_lds(
      (const __attribute__((address_space(1))) u32*)(const void*)g,
      (__attribute__((address_space(3))) u32*)l, 16, 0, 0);
}

// ---------------- weight split: w -> bf16 hi + bf16 lo (+ cnt zero) ----------
__global__ __launch_bounds__(256) void k_wsplit(const float* __restrict__ qw,
    const float* __restrict__ kw, const float* __restrict__ vw,
    const float* __restrict__ lw, u16* __restrict__ wsp, u32* __restrict__ cnt) {
  int idx = blockIdx.x * 256 + threadIdx.x;   // 262144 (4 mats x 65536 float4)
  if (idx == 0) *cnt = 0;
  int mat = idx >> 16;
  int u = idx & 65535;
  const float* W = mat == 0 ? qw : mat == 1 ? kw : mat == 2 ? vw : lw;
  float4 w = ((const float4*)W)[u];
  float wv[4] = {w.x, w.y, w.z, w.w};
  u16 hb[4], lb[4];
#pragma unroll
  for (int c = 0; c < 4; ++c) {
    __bf16 h = (__bf16)wv[c];
    float r = wv[c] - (float)h;
    __bf16 lo = (__bf16)r;
    hb[c] = __builtin_bit_cast(u16, h);
    lb[c] = __builtin_bit_cast(u16, lo);
  }
  u16* base = wsp + (size_t)mat * 524288;          // [mat][plane][e][d]
  ((ushort4*)base)[u]            = make_ushort4(hb[0], hb[1], hb[2], hb[3]);
  ((ushort4*)(base + 262144))[u] = make_ushort4(lb[0], lb[1], lb[2], lb[3]);
}

// ---------------- first LIF: x[t][bi][d] -> xsb[bi*4+t][d] ----------------
__global__ __launch_bounds__(256) void k_lif_first(const float* __restrict__ x,
                                                   u16* __restrict__ xsb) {
  int idx = blockIdx.x * 256 + threadIdx.x;       // bi*128 + d4
  if (idx >= STRIDE4) return;
  const int bi = idx >> 7, d4 = idx & 127;
  const float4* x4 = (const float4*)x;
  ushort4* o4 = (ushort4*)xsb;
  float m[4], s[4];
  float4 v = x4[idx];
  m[0] = v.x; m[1] = v.y; m[2] = v.z; m[3] = v.w;
#pragma unroll
  for (int c = 0; c < 4; ++c) s[c] = spike_of(m[c]);
  o4[(bi * 4 + 0) * 128 + d4] =
      make_ushort4(sbits(s[0]), sbits(s[1]), sbits(s[2]), sbits(s[3]));
#pragma unroll
  for (int t = 1; t < T_; ++t) {
    v = x4[idx + t * STRIDE4];
    float xv[4] = {v.x, v.y, v.z, v.w};
#pragma unroll
    for (int c = 0; c < 4; ++c) {
      m[c] = m[c] * 0.25f * (1.0f - s[c]) + xv[c];
      s[c] = spike_of(m[c]);
    }
    o4[(bi * 4 + t) * 128 + d4] =
        make_ushort4(sbits(s[0]), sbits(s[1]), sbits(s[2]), sbits(s[3]));
  }
}

// ======= shared GEMM core: 128x128 tile, BK=64, 2-barrier loop =======
__device__ __forceinline__ void gemm_core(const u16* __restrict__ Ab,
    const u16* __restrict__ Wp, int row0, int col0, int tid,
    unsigned char* sm, f32x4 (&acc)[4][4]) {
  const u16* gsrc[12];
  int loff[12];
#pragma unroll
  for (int u = 0; u < 12; ++u) {
    if (u < 4) {
      int lin = u * 4096 + tid * 16;
      int r = lin >> 7, slot = (lin >> 4) & 7, gs = slot ^ (r & 7);
      gsrc[u] = Ab + (size_t)(row0 + r) * 512 + gs * 8;
      loff[u] = lin;
    } else {
      int lin = (u - 4) * 4096 + tid * 16;
      int plane = lin >> 14, l3 = lin & 16383;
      int r = l3 >> 7, slot = (l3 >> 4) & 7, gs = slot ^ (r & 7);
      gsrc[u] = Wp + (size_t)plane * 262144 + (size_t)(col0 + r) * 512 + gs * 8;
      loff[u] = 16384 + lin;
    }
  }
  const int lane = tid & 63;
  const int wid = tid >> 6;
  const int wr = wid >> 1, wc = wid & 1;
  const int la = lane & 15, lg = lane >> 4;

  int offA[4][2], offB[2][4][2];
#pragma unroll
  for (int mi = 0; mi < 4; ++mi) {
    int r = wr * 64 + mi * 16 + la;
#pragma unroll
    for (int s = 0; s < 2; ++s)
      offA[mi][s] = r * 128 + ((s * 64 + lg * 16) ^ ((r & 7) << 4));
  }
#pragma unroll
  for (int p = 0; p < 2; ++p)
#pragma unroll
    for (int ni = 0; ni < 4; ++ni) {
      int r = wc * 64 + ni * 16 + la;
#pragma unroll
      for (int s = 0; s < 2; ++s)
        offB[p][ni][s] = 16384 + p * 16384 + r * 128 +
                         ((s * 64 + lg * 16) ^ ((r & 7) << 4));
    }

#pragma unroll
  for (int a = 0; a < 4; ++a)
#pragma unroll
    for (int b = 0; b < 4; ++b) acc[a][b] = (f32x4){0.f, 0.f, 0.f, 0.f};

  for (int k0 = 0; k0 < 8; ++k0) {
#pragma unroll
    for (int u = 0; u < 12; ++u) gll16(gsrc[u] + (k0 << 6), sm + loff[u]);
    __syncthreads();
    uint4 af[4][2];
#pragma unroll
    for (int mi = 0; mi < 4; ++mi)
#pragma unroll
      for (int s = 0; s < 2; ++s)
        af[mi][s] = *(const uint4*)(sm + offA[mi][s]);
#pragma unroll
    for (int p = 0; p < 2; ++p)
#pragma unroll
      for (int s = 0; s < 2; ++s)
#pragma unroll
        for (int ni = 0; ni < 4; ++ni) {
          uint4 bf = *(const uint4*)(sm + offB[p][ni][s]);
#pragma unroll
          for (int mi = 0; mi < 4; ++mi)
            acc[mi][ni] = __builtin_amdgcn_mfma_f32_16x16x32_bf16(
                __builtin_bit_cast(bf16x8, af[mi][s]),
                __builtin_bit_cast(bf16x8, bf), acc[mi][ni], 0, 0, 0);
        }
    __syncthreads();
  }
}

// ------ fused QKV: GEMM + BN + LIF epilogue, LDS-staged coalesced stores ----
__global__ __launch_bounds__(256) void k_gemm_qkv(const u16* __restrict__ Ab,
    const u16* __restrict__ wsp,
    const float* __restrict__ qb2, const float* __restrict__ qg,
    const float* __restrict__ qbe,
    const float* __restrict__ kb2, const float* __restrict__ kg,
    const float* __restrict__ kbe,
    const float* __restrict__ vb2, const float* __restrict__ vg,
    const float* __restrict__ vbe,
    u16* __restrict__ qs, u16* __restrict__ ks, u16* __restrict__ vs,
    u32* __restrict__ list, u32* __restrict__ cnt) {
  __shared__ __align__(16) unsigned char sm[49152];
  const int tid = threadIdx.x;
  const int tz = blockIdx.z;
  const u16* Wp = wsp + (size_t)tz * 524288;
  const float* Bb = tz == 0 ? qb2 : tz == 1 ? kb2 : vb2;
  const float* Gg = tz == 0 ? qg  : tz == 1 ? kg  : vg;
  const float* Be = tz == 0 ? qbe : tz == 1 ? kbe : vbe;
  u16* S          = tz == 0 ? qs  : tz == 1 ? ks  : vs;

  int f = blockIdx.y * 4 + blockIdx.x;
  int tI = (f & 7) * 64 + (f >> 3);
  const int row0 = (tI >> 2) * 128;
  const int col0 = (tI & 3) * 128;

  f32x4 acc[4][4];
  gemm_core(Ab, Wp, row0, col0, tid, sm, acc);

  const int lane = tid & 63;
  const int wid = tid >> 6;
  const int wr = wid >> 1, wc = wid & 1;
  const int la = lane & 15, lg = lane >> 4;

  u16* sm16 = (u16*)sm;                 // 128x128 u16 spike tile (32KB)
#pragma unroll
  for (int ni = 0; ni < 4; ++ni) {
    int cl = wc * 64 + ni * 16 + la;    // local col
    int e = col0 + cl;
    float cs = INV_STD * Gg[e];
    float cb = Bb[e], ct = Be[e];
#pragma unroll
    for (int mi = 0; mi < 4; ++mi) {
      int rl = wr * 64 + mi * 16 + lg * 4;   // local row base (bi*4 aligned)
      int bi = (row0 + rl) >> 2;
      float m = 0.f, s = 0.f;
      int fl = 0;
#pragma unroll
      for (int p = 0; p < 4; ++p) {          // p == t
        float pre = (acc[mi][ni][p] + cb) * cs + ct;
        if (p == 0) m = pre;
        else m = m * 0.25f * (1.0f - s) + pre;
        s = spike_of(m);
        if (fabsf(m - 0.5f) < EPS_FLAG) fl = 1;
        sm16[(rl + p) * 128 + cl] = sbits(s);
      }
      if (fl) {
        u32 pos = atomicAdd(cnt, 1u);
        if (pos < LIST_CAP)
          list[pos] = ((u32)tz << 21) | (u32)(bi * 512 + e);
      }
    }
  }
  __syncthreads();
  // coalesced write-out: 8 passes x 16 rows, 16B per lane
#pragma unroll
  for (int ps = 0; ps < 8; ++ps) {
    int rr = ps * 16 + (tid >> 4);
    int c8 = (tid & 15) * 8;
    uint4 vv = *(const uint4*)(sm16 + rr * 128 + c8);
    *(uint4*)(S + (size_t)(row0 + rr) * 512 + col0 + c8) = vv;
  }
}

// -------- last GEMM + BN -> fp32 out [t][bi][d], LDS-staged stores ----------
__global__ __launch_bounds__(256) void k_gemm_out(const u16* __restrict__ Ab,
    const u16* __restrict__ Wp, const float* __restrict__ bias,
    const float* __restrict__ gamma, const float* __restrict__ beta,
    float* __restrict__ Y) {
  __shared__ __align__(16) unsigned char sm[49152];
  const int tid = threadIdx.x;
  int f = blockIdx.y * 4 + blockIdx.x;
  int tI = (f & 7) * 64 + (f >> 3);
  const int row0 = (tI >> 2) * 128;
  const int col0 = (tI & 3) * 128;

  f32x4 acc[4][4];
  gemm_core(Ab, Wp, row0, col0, tid, sm, acc);

  const int lane = tid & 63;
  const int wid = tid >> 6;
  const int wr = wid >> 1, wc = wid & 1;
  const int la = lane & 15, lg = lane >> 4;

  float* sm32 = (float*)sm;             // 64x128 f32 tile per pass (32KB)
#pragma unroll
  for (int h = 0; h < 2; ++h) {
    if (wr == h) {
#pragma unroll
      for (int ni = 0; ni < 4; ++ni) {
        int cl = wc * 64 + ni * 16 + la;
        int e = col0 + cl;
        float cs = INV_STD * gamma[e];
        float cb = bias[e], ct = beta[e];
#pragma unroll
        for (int mi = 0; mi < 4; ++mi) {
          int rb = mi * 16 + lg * 4;         // local row within pass
#pragma unroll
          for (int p = 0; p < 4; ++p)
            sm32[(rb + p) * 128 + cl] = (acc[mi][ni][p] + cb) * cs + ct;
        }
      }
    }
    __syncthreads();
    // write 64 rows coalesced: 4 threads per row, 128B each
    int rl = tid >> 2;                   // 0..63
    int q0 = (tid & 3) * 32;             // float offset
    int gr = row0 + h * 64 + rl;         // global spike-row = bi*4+p
    int bi = gr >> 2, p = gr & 3;
    float* dst = Y + ((size_t)p * BI_ + bi) * 512 + col0 + q0;
    const float* srcl = sm32 + rl * 128 + q0;
#pragma unroll
    for (int u = 0; u < 8; ++u)
      ((uint4*)dst)[u] = ((const uint4*)srcl)[u];
    __syncthreads();
  }
}

// ------- fixup: quad-per-item, exact serial chain per t, shfl-combine -------
__device__ __forceinline__ void consume32_1(const float4 (&wb)[8],
                                            const uint4 (&ab)[4], float& c) {
#pragma unroll
  for (int u = 0; u < 8; ++u) {           // u = group of 4 consecutive j
    float4 w = wb[u];
    uint4 tt = ab[u >> 1];
    u32 a = (u & 1) ? tt.z : tt.x, b = (u & 1) ? tt.w : tt.y;
    c += (a & 0xFFFFu) ? w.x : 0.0f;      // strict ascending-j order
    c += (a >> 16)     ? w.y : 0.0f;
    c += (b & 0xFFFFu) ? w.z : 0.0f;
    c += (b >> 16)     ? w.w : 0.0f;
  }
}

__global__ __launch_bounds__(128) void k_fixup_c(const u16* __restrict__ xsb,
    u16* __restrict__ qs, u16* __restrict__ ks, u16* __restrict__ vs,
    const float* __restrict__ qw, const float* __restrict__ qb2,
    const float* __restrict__ qg, const float* __restrict__ qbe,
    const float* __restrict__ kw, const float* __restrict__ kb2,
    const float* __restrict__ kg, const float* __restrict__ kbe,
    const float* __restrict__ vw, const float* __restrict__ vb2,
    const float* __restrict__ vg, const float* __restrict__ vbe,
    const u32* __restrict__ list, const u32* __restrict__ cnt) {
  u32 n = *cnt;
  if (n > LIST_CAP) n = LIST_CAP;
  u32 tot = n * 4;
  for (u32 ii = blockIdx.x * 128 + threadIdx.x; ii < tot;
       ii += gridDim.x * 128) {
    u32 i = ii >> 2;
    int t = (int)(ii & 3);
    u32 e = list[i];
    int tz = (int)(e >> 21);
    int col = (int)(e & 0x1FFFFFu);
    int bi = col >> 9, d = col & 511;
    const float* W  = tz == 0 ? qw  : tz == 1 ? kw  : vw;
    const float* Bb = tz == 0 ? qb2 : tz == 1 ? kb2 : vb2;
    const float* Gg = tz == 0 ? qg  : tz == 1 ? kg  : vg;
    const float* Be = tz == 0 ? qbe : tz == 1 ? kbe : vbe;
    u16* S          = tz == 0 ? qs  : tz == 1 ? ks  : vs;
    const float4* w4 = (const float4*)(W + (size_t)d * 512);          // 128
    const uint4*  R  = (const uint4*)(xsb + ((size_t)bi * 4 + t) * 512); // 32

    float4 wA[8], wB[8];
    uint4 aA[4], aB[4];
#pragma unroll
    for (int u = 0; u < 8; ++u) wA[u] = w4[u];
#pragma unroll
    for (int u = 0; u < 4; ++u) aA[u] = R[u];
    float c = 0.f;
#pragma unroll
    for (int ch = 0; ch < 16; ++ch) {     // 16 chunks x 32 j
      if ((ch & 1) == 0) {
        if (ch + 1 < 16) {
          int wb0 = (ch + 1) * 8, ab0 = (ch + 1) * 4;
#pragma unroll
          for (int u = 0; u < 8; ++u) wB[u] = w4[wb0 + u];
#pragma unroll
          for (int u = 0; u < 4; ++u) aB[u] = R[ab0 + u];
        }
        consume32_1(wA, aA, c);
      } else {
        if (ch + 1 < 16) {
          int wb0 = (ch + 1) * 8, ab0 = (ch + 1) * 4;
#pragma unroll
          for (int u = 0; u < 8; ++u) wA[u] = w4[wb0 + u];
#pragma unroll
          for (int u = 0; u < 4; ++u) aA[u] = R[ab0 + u];
        }
        consume32_1(wB, aB, c);
      }
    }
    int lane = threadIdx.x & 63;
    int qb = lane & ~3;
    float cq[4];
    cq[0] = __shfl(c, qb + 0, 64);
    cq[1] = __shfl(c, qb + 1, 64);
    cq[2] = __shfl(c, qb + 2, 64);
    cq[3] = __shfl(c, qb + 3, 64);
    float cs = INV_STD * Gg[d];
    float cb = Bb[d], ct = Be[d];
    float m = 0.f, s = 0.f;
    u16 myb = 0;
#pragma unroll
    for (int t2 = 0; t2 < 4; ++t2) {
      float pre = (cq[t2] + cb) * cs + ct;   // identical to GEMM epilogue
      if (t2 == 0) m = pre;
      else m = m * 0.25f * (1.0f - s) + pre;
      s = spike_of(m);
      if (t2 == t) myb = sbits(s);
    }
    S[((size_t)bi * 4 + t) * 512 + d] = myb;
  }
}

// ---------------- banded positional mixing + attn_lif ----------------
__global__ __launch_bounds__(256) void k_attn(const u16* __restrict__ qs,
    const u16* __restrict__ ks, const u16* __restrict__ vs,
    const float* __restrict__ pos_bias, u16* __restrict__ sout) {
  int idx = blockIdx.x * 256 + threadIdx.x;     // bi*128 + d4
  if (idx >= STRIDE4) return;
  const int d4 = idx & 127;
  const int bi = idx >> 7;
  const int i = bi & (L_ - 1);
  const int wmax = i < 7 ? i : 7;

  float pbv[8];
  const float* pbrow = pos_bias + (size_t)i * L_ + i;
  for (int w = 0; w <= wmax; ++w) pbv[w] = pbrow[-w];

  const ushort4* k4 = (const ushort4*)ks;
  const ushort4* v4 = (const ushort4*)vs;
  const ushort4* q4 = (const ushort4*)qs;
  float pre[T_][4];

#pragma unroll
  for (int t = 0; t < T_; ++t) {
    float sum[4] = {0.f, 0.f, 0.f, 0.f};
    for (int w = wmax; w >= 0; --w) {   // ascending j = i-w
      int rj = ((bi - w) * 4 + t) * 128 + d4;
      ushort4 ku = k4[rj];
      ushort4 vu = v4[rj];
      sum[0] += (ku.x && vu.x) ? pbv[w] : 0.0f;
      sum[1] += (ku.y && vu.y) ? pbv[w] : 0.0f;
      sum[2] += (ku.z && vu.z) ? pbv[w] : 0.0f;
      sum[3] += (ku.w && vu.w) ? pbv[w] : 0.0f;
    }
    ushort4 qu = q4[(bi * 4 + t) * 128 + d4];
    pre[t][0] = qu.x ? sum[0] : 0.0f;
    pre[t][1] = qu.y ? sum[1] : 0.0f;
    pre[t][2] = qu.z ? sum[2] : 0.0f;
    pre[t][3] = qu.w ? sum[3] : 0.0f;
  }

  ushort4* s4 = (ushort4*)sout;
  float m[4], s[4];
#pragma unroll
  for (int c = 0; c < 4; ++c) { m[c] = pre[0][c]; s[c] = spike_of(m[c]); }
  s4[(bi * 4 + 0) * 128 + d4] =
      make_ushort4(sbits(s[0]), sbits(s[1]), sbits(s[2]), sbits(s[3]));
#pragma unroll
  for (int t = 1; t < T_; ++t) {
#pragma unroll
    for (int c = 0; c < 4; ++c) {
      m[c] = m[c] * 0.25f * (1.0f - s[c]) + pre[t][c];
      s[c] = spike_of(m[c]);
    }
    s4[(bi * 4 + t) * 128 + d4] =
        make_ushort4(sbits(s[0]), sbits(s[1]), sbits(s[2]), sbits(s[3]));
  }
}

extern "C" void kernel_launch(void* const* d_in, const int* in_sizes, int n_in,
                              void* d_out, int out_size, void* d_ws, size_t ws_size,
                              hipStream_t stream) {
  (void)in_sizes; (void)n_in; (void)out_size; (void)ws_size;
  const float* x        = (const float*)d_in[0];
  const float* pos_bias = (const float*)d_in[1];
  const float* q_w    = (const float*)d_in[2];
  const float* q_b    = (const float*)d_in[3];
  const float* q_g    = (const float*)d_in[4];
  const float* q_beta = (const float*)d_in[5];
  const float* k_w    = (const float*)d_in[6];
  const float* k_b    = (const float*)d_in[7];
  const float* k_g    = (const float*)d_in[8];
  const float* k_beta = (const float*)d_in[9];
  const float* v_w    = (const float*)d_in[10];
  const float* v_b    = (const float*)d_in[11];
  const float* v_g    = (const float*)d_in[12];
  const float* v_beta = (const float*)d_in[13];
  const float* last_w    = (const float*)d_in[14];
  const float* last_b    = (const float*)d_in[15];
  const float* last_g    = (const float*)d_in[16];
  const float* last_beta = (const float*)d_in[17];
  float* out = (float*)d_out;

  char* ws = (char*)d_ws;
  u16*   xsb  = (u16*)(ws + 0);
  u16*   qs   = (u16*)(ws + 16777216);
  u16*   ks   = (u16*)(ws + 33554432);
  u16*   vs   = (u16*)(ws + 50331648);
  u16*   sA   = (u16*)(ws + 67108864);
  u16*   wsp  = (u16*)(ws + 100663296);
  u32*   list = (u32*)(ws + 104857600);    // 20 MB cap
  u32*   cnt  = (u32*)(ws + 124857600);

  k_wsplit<<<1024, 256, 0, stream>>>(q_w, k_w, v_w, last_w, wsp, cnt);
  k_lif_first<<<2048, 256, 0, stream>>>(x, xsb);

  dim3 gq(4, 128, 3);
  k_gemm_qkv<<<gq, 256, 0, stream>>>(xsb, wsp,
      q_b, q_g, q_beta, k_b, k_g, k_beta, v_b, v_g, v_beta,
      qs, ks, vs, list, cnt);

  k_fixup_c<<<2048, 128, 0, stream>>>(xsb, qs, ks, vs,
      q_w, q_b, q_g, q_beta, k_w, k_b, k_g, k_beta, v_w, v_b, v_g, v_beta,
      list, cnt);

  k_attn<<<2048, 256, 0, stream>>>(qs, ks, vs, pos_bias, sA);

  dim3 gg(4, 128);
  k_gemm_out<<<gg, 256, 0, stream>>>(sA, wsp + 3 * 524288,
                                     last_b, last_g, last_beta, out);
}